// Round 1
// baseline (511.633 us; speedup 1.0000x reference)
//
#include <hip/hip_runtime.h>
#include <hip/hip_bf16.h>

#define N_NODES 40000
#define N_EDGES 640000
#define N_GRAPH 64
#define C_IN 64
#define HID 128
#define OUT 128
#define ZDIM 192   // HID + C_IN

// ---------------------------------------------------------------------------
// K1: collapse the affine chains.
// wv[c], bv[c]:  h = x*wv + bv   (x@W1@W2@W3 chain)
// wc[k], bcv[k]: hW1 = x*wc + bcv (h @ Wc1)
__global__ __launch_bounds__(256) void k_prep(
    const float* __restrict__ W1, const float* __restrict__ b1,
    const float* __restrict__ W2, const float* __restrict__ b2,
    const float* __restrict__ W3, const float* __restrict__ b3,
    const float* __restrict__ Wc1,
    float* __restrict__ wv, float* __restrict__ bv,
    float* __restrict__ wc, float* __restrict__ bcv) {
  __shared__ float t1[256], u1[256], wv_s[64], bv_s[64];
  int t = threadIdx.x;
  float s1 = 0.f, s2 = 0.f;
  for (int j = 0; j < 64; ++j) {
    float w = W2[j * 256 + t];
    s1 += W1[j] * w;
    s2 += b1[j] * w;
  }
  t1[t] = s1;
  u1[t] = s2 + b2[t];
  __syncthreads();
  if (t < 64) {
    float a = 0.f, bb = 0.f;
    for (int k = 0; k < 256; ++k) {
      float w = W3[k * 64 + t];
      a += t1[k] * w;
      bb += u1[k] * w;
    }
    bb += b3[t];
    wv_s[t] = a; bv_s[t] = bb;
    wv[t] = a;  bv[t] = bb;
  }
  __syncthreads();
  if (t < 128) {
    float a = 0.f, bb = 0.f;
    for (int c = 0; c < 64; ++c) {
      float w = Wc1[c * 128 + t];
      a += wv_s[c] * w;
      bb += bv_s[c] * w;
    }
    wc[t] = a; bcv[t] = bb;
  }
}

// K2: init scratch (harness poisons ws; everything we read must be written)
__global__ void k_init(int* __restrict__ deg, int* __restrict__ cursor,
                       float* __restrict__ gsum, int* __restrict__ gcnt) {
  int i = blockIdx.x * blockDim.x + threadIdx.x;
  if (i < N_NODES) { deg[i] = 1; cursor[i] = 0; }
  if (i < N_GRAPH * OUT) gsum[i] = 0.f;
  if (i < N_GRAPH) gcnt[i] = 0;
}

// K3: in-degree (+1 self loop already in init)
__global__ void k_deg(const int* __restrict__ dst, int* __restrict__ deg) {
  int e = blockIdx.x * blockDim.x + threadIdx.x;
  if (e < N_EDGES) atomicAdd(&deg[dst[e]], 1);
}

// K4: dinv + self-loop seed of the scalar conv1 aggregates
__global__ void k_dinv(const int* __restrict__ deg, const float* __restrict__ x,
                       float* __restrict__ dinv, float* __restrict__ sx,
                       float* __restrict__ sd) {
  int v = blockIdx.x * blockDim.x + threadIdx.x;
  if (v < N_NODES) {
    float dv = 1.0f / sqrtf((float)deg[v]);
    dinv[v] = dv;
    sx[v] = dv * x[v];
    sd[v] = dv;
  }
}

// K5: conv1 edge aggregation — SCALARS only (the 128-wide conv is affine in these)
__global__ void k_conv1(const int* __restrict__ src, const int* __restrict__ dst,
                        const float* __restrict__ x, const float* __restrict__ dinv,
                        float* __restrict__ sx, float* __restrict__ sd) {
  int e = blockIdx.x * blockDim.x + threadIdx.x;
  if (e < N_EDGES) {
    int s = src[e], d = dst[e];
    float ds = dinv[s];
    atomicAdd(&sx[d], ds * x[s]);
    atomicAdd(&sd[d], ds);
  }
}

// K6a/b/c: exclusive prefix sum of (deg-1) -> CSR offsets. chunk = 1024/block.
__global__ __launch_bounds__(256) void k_scanA(const int* __restrict__ deg,
                                               int* __restrict__ off,
                                               int* __restrict__ bsum) {
  __shared__ int s[256];
  int t = threadIdx.x;
  int base = blockIdx.x * 1024;
  int vals[4];
  int loc = 0;
  for (int i = 0; i < 4; ++i) {
    int v = base + t * 4 + i;
    int d = (v < N_NODES) ? deg[v] - 1 : 0;
    vals[i] = loc;
    loc += d;
  }
  s[t] = loc;
  __syncthreads();
  for (int ofs = 1; ofs < 256; ofs <<= 1) {
    int a = (t >= ofs) ? s[t - ofs] : 0;
    __syncthreads();
    s[t] += a;
    __syncthreads();
  }
  int texcl = s[t] - loc;
  for (int i = 0; i < 4; ++i) {
    int v = base + t * 4 + i;
    if (v < N_NODES) off[v] = texcl + vals[i];
  }
  if (t == 255) bsum[blockIdx.x] = s[255];
}

__global__ __launch_bounds__(64) void k_scanB(int* __restrict__ bsum,
                                              int* __restrict__ off, int nb) {
  __shared__ int s[64];
  int t = threadIdx.x;
  int v = (t < nb) ? bsum[t] : 0;
  s[t] = v;
  __syncthreads();
  for (int ofs = 1; ofs < 64; ofs <<= 1) {
    int a = (t >= ofs) ? s[t - ofs] : 0;
    __syncthreads();
    s[t] += a;
    __syncthreads();
  }
  if (t < nb) bsum[t] = s[t] - v;
  if (t == 63) off[N_NODES] = s[63];
}

__global__ void k_scanC(int* __restrict__ off, const int* __restrict__ bsum) {
  int v = blockIdx.x * blockDim.x + threadIdx.x;
  if (v < N_NODES) off[v] += bsum[v >> 10];
}

// K7: CSR fill (bucket by dst)
__global__ void k_fill(const int* __restrict__ src, const int* __restrict__ dst,
                       const int* __restrict__ off, int* __restrict__ cursor,
                       int* __restrict__ csr_src) {
  int e = blockIdx.x * blockDim.x + threadIdx.x;
  if (e < N_EDGES) {
    int d = dst[e];
    int p = atomicAdd(&cursor[d], 1);
    csr_src[off[d] + p] = src[e];
  }
}

// K10: per-graph node counts
__global__ void k_cnt(const int* __restrict__ batch, int* __restrict__ gcnt) {
  int v = blockIdx.x * blockDim.x + threadIdx.x;
  if (v < N_NODES) atomicAdd(&gcnt[batch[v]], 1);
}

// K8: build z[v] = relu(concat(out1[v], x1[root]))  (on the fly, never materialized)
//     hW2g[v] = dinv[v] * (z[v] @ Wc2)   [N,128]
#define NPB8 8
__global__ __launch_bounds__(128) void k_mlp2(
    const float* __restrict__ x, const int* __restrict__ batch,
    const int* __restrict__ root, const float* __restrict__ dinv,
    const float* __restrict__ sx, const float* __restrict__ sd,
    const float* __restrict__ wc, const float* __restrict__ bcv,
    const float* __restrict__ bc1, const float* __restrict__ wv,
    const float* __restrict__ bv, const float* __restrict__ Wc2,
    float* __restrict__ hW2g) {
  __shared__ float z[NPB8][ZDIM];
  __shared__ float a_s[NPB8], c_s[NPB8], xr_s[NPB8], dv_s[NPB8];
  int t = threadIdx.x;
  int v0 = blockIdx.x * NPB8;
  if (t < NPB8) {
    int v = v0 + t;
    if (v < N_NODES) {
      float dv = dinv[v];
      dv_s[t] = dv;
      a_s[t] = dv * sx[v];
      c_s[t] = dv * sd[v];
      int b = batch[v];
      xr_s[t] = x[root[b]];
    } else {
      dv_s[t] = 0.f; a_s[t] = 0.f; c_s[t] = 0.f; xr_s[t] = 0.f;
    }
  }
  __syncthreads();
  for (int idx = t; idx < NPB8 * ZDIM; idx += 128) {
    int m = idx / ZDIM, j = idx - m * ZDIM;
    float val;
    if (j < HID)
      val = a_s[m] * wc[j] + c_s[m] * bcv[j] + bc1[j];
    else {
      int cc = j - HID;
      val = xr_s[m] * wv[cc] + bv[cc];
    }
    z[m][j] = val > 0.f ? val : 0.f;
  }
  __syncthreads();
  float acc[NPB8];
#pragma unroll
  for (int m = 0; m < NPB8; ++m) acc[m] = 0.f;
  int o = t;
  for (int j = 0; j < ZDIM; ++j) {
    float w = Wc2[j * 128 + o];
#pragma unroll
    for (int m = 0; m < NPB8; ++m) acc[m] += z[m][j] * w;
  }
#pragma unroll
  for (int m = 0; m < NPB8; ++m) {
    int v = v0 + m;
    if (v < N_NODES) hW2g[(size_t)v * 128 + o] = dv_s[m] * acc[m];
  }
}

// K9: conv2 gather (CSR) + relu + per-graph partial-sum flush (batch is sorted)
#define GNPB 16
__global__ __launch_bounds__(128) void k_conv2(
    const int* __restrict__ off, const int* __restrict__ csr,
    const float* __restrict__ hW2g, const float* __restrict__ dinv,
    const float* __restrict__ bc2, const int* __restrict__ batch,
    float* __restrict__ gsum) {
  int k = threadIdx.x;
  int v0 = blockIdx.x * GNPB;
  if (v0 >= N_NODES) return;
  int vend = v0 + GNPB;
  if (vend > N_NODES) vend = N_NODES;
  float bk = bc2[k];
  float local = 0.f;
  int cur_b = batch[v0];
  for (int v = v0; v < vend; ++v) {
    int b = batch[v];
    if (b != cur_b) {
      atomicAdd(&gsum[cur_b * 128 + k], local);
      local = 0.f;
      cur_b = b;
    }
    int o0 = off[v], o1 = off[v + 1];
    float acc = hW2g[(size_t)v * 128 + k];
    for (int i = o0; i < o1; ++i) {
      int s = csr[i];
      acc += hW2g[(size_t)s * 128 + k];
    }
    float val = dinv[v] * acc + bk;
    local += val > 0.f ? val : 0.f;
  }
  atomicAdd(&gsum[cur_b * 128 + k], local);
}

// K11: finalize — mean of relu(out2) half + closed-form out1[root] half
__global__ __launch_bounds__(128) void k_final(
    const float* __restrict__ gsum, const int* __restrict__ gcnt,
    const int* __restrict__ root, const float* __restrict__ dinv,
    const float* __restrict__ sx, const float* __restrict__ sd,
    const float* __restrict__ wc, const float* __restrict__ bcv,
    const float* __restrict__ bc1, float* __restrict__ out) {
  int b = blockIdx.x, k = threadIdx.x;
  float cnt = (float)gcnt[b];
  if (cnt < 1.f) cnt = 1.f;
  out[b * 256 + k] = gsum[b * 128 + k] / cnt;
  int r = root[b];
  float dr = dinv[r];
  float a = dr * sx[r], c = dr * sd[r];
  out[b * 256 + 128 + k] = a * wc[k] + c * bcv[k] + bc1[k];
}

extern "C" void kernel_launch(void* const* d_in, const int* in_sizes, int n_in,
                              void* d_out, int out_size, void* d_ws, size_t ws_size,
                              hipStream_t stream) {
  const float* x   = (const float*)d_in[0];
  const int* ei    = (const int*)d_in[1];
  const int* batch = (const int*)d_in[2];
  const int* root  = (const int*)d_in[3];
  const float* W1  = (const float*)d_in[4];
  const float* b1  = (const float*)d_in[5];
  const float* W2  = (const float*)d_in[6];
  const float* b2  = (const float*)d_in[7];
  const float* W3  = (const float*)d_in[8];
  const float* b3  = (const float*)d_in[9];
  const float* Wc1 = (const float*)d_in[10];
  const float* bc1 = (const float*)d_in[11];
  const float* Wc2 = (const float*)d_in[12];
  const float* bc2 = (const float*)d_in[13];
  float* out = (float*)d_out;

  const int* src = ei;            // edge_index[0]
  const int* dst = ei + N_EDGES;  // edge_index[1]

  // workspace carve-up (256B aligned)
  char* base = (char*)d_ws;
  size_t pos = 0;
  auto alloc = [&](size_t bytes) {
    size_t o = pos;
    pos = (pos + bytes + 255) & ~(size_t)255;
    return (void*)(base + o);
  };
  float* wv   = (float*)alloc(64 * 4);
  float* bv   = (float*)alloc(64 * 4);
  float* wc   = (float*)alloc(128 * 4);
  float* bcv  = (float*)alloc(128 * 4);
  float* dinv = (float*)alloc((size_t)N_NODES * 4);
  float* sx   = (float*)alloc((size_t)N_NODES * 4);
  float* sd   = (float*)alloc((size_t)N_NODES * 4);
  int* deg    = (int*)alloc((size_t)N_NODES * 4);
  int* cursor = (int*)alloc((size_t)N_NODES * 4);
  int* off    = (int*)alloc((size_t)(N_NODES + 1) * 4);
  int* bsum   = (int*)alloc(64 * 4);
  int* csr    = (int*)alloc((size_t)N_EDGES * 4);
  float* hW2g = (float*)alloc((size_t)N_NODES * 128 * 4);
  float* gsum = (float*)alloc((size_t)N_GRAPH * 128 * 4);
  int* gcnt   = (int*)alloc((size_t)N_GRAPH * 4);
  (void)ws_size; (void)in_sizes; (void)n_in; (void)out_size;

  const int TB = 256;
  int gN = (N_NODES + TB - 1) / TB;
  int gE = (N_EDGES + TB - 1) / TB;
  int nScanBlk = (N_NODES + 1023) / 1024;  // 40

  hipLaunchKernelGGL(k_prep, dim3(1), dim3(256), 0, stream,
                     W1, b1, W2, b2, W3, b3, Wc1, wv, bv, wc, bcv);
  hipLaunchKernelGGL(k_init, dim3(gN), dim3(TB), 0, stream, deg, cursor, gsum, gcnt);
  hipLaunchKernelGGL(k_deg, dim3(gE), dim3(TB), 0, stream, dst, deg);
  hipLaunchKernelGGL(k_dinv, dim3(gN), dim3(TB), 0, stream, deg, x, dinv, sx, sd);
  hipLaunchKernelGGL(k_conv1, dim3(gE), dim3(TB), 0, stream, src, dst, x, dinv, sx, sd);
  hipLaunchKernelGGL(k_scanA, dim3(nScanBlk), dim3(256), 0, stream, deg, off, bsum);
  hipLaunchKernelGGL(k_scanB, dim3(1), dim3(64), 0, stream, bsum, off, nScanBlk);
  hipLaunchKernelGGL(k_scanC, dim3(gN), dim3(TB), 0, stream, off, bsum);
  hipLaunchKernelGGL(k_fill, dim3(gE), dim3(TB), 0, stream, src, dst, off, cursor, csr);
  hipLaunchKernelGGL(k_cnt, dim3(gN), dim3(TB), 0, stream, batch, gcnt);
  hipLaunchKernelGGL(k_mlp2, dim3((N_NODES + NPB8 - 1) / NPB8), dim3(128), 0, stream,
                     x, batch, root, dinv, sx, sd, wc, bcv, bc1, wv, bv, Wc2, hW2g);
  hipLaunchKernelGGL(k_conv2, dim3((N_NODES + GNPB - 1) / GNPB), dim3(128), 0, stream,
                     off, csr, hW2g, dinv, bc2, batch, gsum);
  hipLaunchKernelGGL(k_final, dim3(N_GRAPH), dim3(128), 0, stream,
                     gsum, gcnt, root, dinv, sx, sd, wc, bcv, bc1, out);
}

// Round 2
// 266.828 us; speedup vs baseline: 1.9175x; 1.9175x over previous
//
#include <hip/hip_runtime.h>
#include <hip/hip_bf16.h>

#define N_NODES 40000
#define N_EDGES 640000
#define N_GRAPH 64
#define C_IN 64
#define HID 128
#define OUT 128
#define ZDIM 192   // HID + C_IN

// ---------------------------------------------------------------------------
// K1: collapse the affine chains.
// wv[c], bv[c]:  h = x*wv + bv   (x@W1@W2@W3 chain)
// wc[k], bcv[k]: hW1 = x*wc + bcv (h @ Wc1)
__global__ __launch_bounds__(256) void k_prep(
    const float* __restrict__ W1, const float* __restrict__ b1,
    const float* __restrict__ W2, const float* __restrict__ b2,
    const float* __restrict__ W3, const float* __restrict__ b3,
    const float* __restrict__ Wc1,
    float* __restrict__ wv, float* __restrict__ bv,
    float* __restrict__ wc, float* __restrict__ bcv) {
  __shared__ float t1[256], u1[256], wv_s[64], bv_s[64];
  int t = threadIdx.x;
  float s1 = 0.f, s2 = 0.f;
  for (int j = 0; j < 64; ++j) {
    float w = W2[j * 256 + t];
    s1 += W1[j] * w;
    s2 += b1[j] * w;
  }
  t1[t] = s1;
  u1[t] = s2 + b2[t];
  __syncthreads();
  if (t < 64) {
    float a = 0.f, bb = 0.f;
    for (int k = 0; k < 256; ++k) {
      float w = W3[k * 64 + t];
      a += t1[k] * w;
      bb += u1[k] * w;
    }
    bb += b3[t];
    wv_s[t] = a; bv_s[t] = bb;
    wv[t] = a;  bv[t] = bb;
  }
  __syncthreads();
  if (t < 128) {
    float a = 0.f, bb = 0.f;
    for (int c = 0; c < 64; ++c) {
      float w = Wc1[c * 128 + t];
      a += wv_s[c] * w;
      bb += bv_s[c] * w;
    }
    wc[t] = a; bcv[t] = bb;
  }
}

// K2: init scratch (harness poisons ws; everything we read must be written)
__global__ void k_init(int* __restrict__ deg, int* __restrict__ cursor,
                       float* __restrict__ gsum) {
  int i = blockIdx.x * blockDim.x + threadIdx.x;
  if (i < N_NODES) { deg[i] = 1; cursor[i] = 0; }
  if (i < N_GRAPH * OUT) gsum[i] = 0.f;
}

// K3: in-degree (+1 self loop already in init)
__global__ void k_deg(const int* __restrict__ dst, int* __restrict__ deg) {
  int e = blockIdx.x * blockDim.x + threadIdx.x;
  if (e < N_EDGES) atomicAdd(&deg[dst[e]], 1);
}

// K4: dinv
__global__ void k_dinv(const int* __restrict__ deg, float* __restrict__ dinv) {
  int v = blockIdx.x * blockDim.x + threadIdx.x;
  if (v < N_NODES) dinv[v] = 1.0f / sqrtf((float)deg[v]);
}

// K6a/b/c: exclusive prefix sum of (deg-1) -> CSR offsets. chunk = 1024/block.
__global__ __launch_bounds__(256) void k_scanA(const int* __restrict__ deg,
                                               int* __restrict__ off,
                                               int* __restrict__ bsum) {
  __shared__ int s[256];
  int t = threadIdx.x;
  int base = blockIdx.x * 1024;
  int vals[4];
  int loc = 0;
  for (int i = 0; i < 4; ++i) {
    int v = base + t * 4 + i;
    int d = (v < N_NODES) ? deg[v] - 1 : 0;
    vals[i] = loc;
    loc += d;
  }
  s[t] = loc;
  __syncthreads();
  for (int ofs = 1; ofs < 256; ofs <<= 1) {
    int a = (t >= ofs) ? s[t - ofs] : 0;
    __syncthreads();
    s[t] += a;
    __syncthreads();
  }
  int texcl = s[t] - loc;
  for (int i = 0; i < 4; ++i) {
    int v = base + t * 4 + i;
    if (v < N_NODES) off[v] = texcl + vals[i];
  }
  if (t == 255) bsum[blockIdx.x] = s[255];
}

__global__ __launch_bounds__(64) void k_scanB(int* __restrict__ bsum,
                                              int* __restrict__ off, int nb) {
  __shared__ int s[64];
  int t = threadIdx.x;
  int v = (t < nb) ? bsum[t] : 0;
  s[t] = v;
  __syncthreads();
  for (int ofs = 1; ofs < 64; ofs <<= 1) {
    int a = (t >= ofs) ? s[t - ofs] : 0;
    __syncthreads();
    s[t] += a;
    __syncthreads();
  }
  if (t < nb) bsum[t] = s[t] - v;
  if (t == 63) off[N_NODES] = s[63];
}

__global__ void k_scanC(int* __restrict__ off, const int* __restrict__ bsum) {
  int v = blockIdx.x * blockDim.x + threadIdx.x;
  if (v < N_NODES) off[v] += bsum[v >> 10];
}

// K7: CSR fill (bucket by dst)
__global__ void k_fill(const int* __restrict__ src, const int* __restrict__ dst,
                       const int* __restrict__ off, int* __restrict__ cursor,
                       int* __restrict__ csr_src) {
  int e = blockIdx.x * blockDim.x + threadIdx.x;
  if (e < N_EDGES) {
    int d = dst[e];
    int p = atomicAdd(&cursor[d], 1);
    csr_src[off[d] + p] = src[e];
  }
}

// K5': conv1 scalar aggregates via CSR gather (no atomics).
// 4 lanes per node; sx[v] = dv*x[v] + sum dinv[s]*x[s]; sd likewise.
__global__ __launch_bounds__(256) void k_sxsd(
    const int* __restrict__ off, const int* __restrict__ csr,
    const float* __restrict__ x, const float* __restrict__ dinv,
    float* __restrict__ sx, float* __restrict__ sd) {
  int t = threadIdx.x;
  int g = t >> 2;
  int l = t & 3;
  int v = blockIdx.x * 64 + g;
  if (v >= N_NODES) return;
  int o0 = off[v], o1 = off[v + 1];
  float ax = 0.f, ad = 0.f;
  for (int i = o0 + l; i < o1; i += 4) {
    int s = csr[i];
    float ds = dinv[s];
    ax += ds * x[s];
    ad += ds;
  }
  ax += __shfl_xor(ax, 1, 4); ad += __shfl_xor(ad, 1, 4);
  ax += __shfl_xor(ax, 2, 4); ad += __shfl_xor(ad, 2, 4);
  if (l == 0) {
    float dv = dinv[v];
    sx[v] = ax + dv * x[v];
    sd[v] = ad + dv;
  }
}

// K10': per-graph segment boundaries (batch is SORTED -> no atomics).
// start[b] = first index v with batch[v] >= b; start[N_GRAPH] = N.
__global__ void k_bounds(const int* __restrict__ batch, int* __restrict__ start) {
  int v = blockIdx.x * blockDim.x + threadIdx.x;
  if (v >= N_NODES) return;
  int bv = batch[v];
  if (v == 0) {
    for (int b = 0; b <= bv; ++b) start[b] = 0;
  } else {
    int bp = batch[v - 1];
    for (int b = bp + 1; b <= bv; ++b) start[b] = v;
  }
  if (v == N_NODES - 1) {
    for (int b = bv + 1; b <= N_GRAPH; ++b) start[b] = N_NODES;
  }
}

// K8: build z[v] = relu(concat(out1[v], x1[root]))  (on the fly, never materialized)
//     hW2g[v] = dinv[v] * (z[v] @ Wc2)   [N,128]
#define NPB8 8
__global__ __launch_bounds__(128) void k_mlp2(
    const float* __restrict__ x, const int* __restrict__ batch,
    const int* __restrict__ root, const float* __restrict__ dinv,
    const float* __restrict__ sx, const float* __restrict__ sd,
    const float* __restrict__ wc, const float* __restrict__ bcv,
    const float* __restrict__ bc1, const float* __restrict__ wv,
    const float* __restrict__ bv, const float* __restrict__ Wc2,
    float* __restrict__ hW2g) {
  __shared__ float z[NPB8][ZDIM];
  __shared__ float a_s[NPB8], c_s[NPB8], xr_s[NPB8], dv_s[NPB8];
  int t = threadIdx.x;
  int v0 = blockIdx.x * NPB8;
  if (t < NPB8) {
    int v = v0 + t;
    if (v < N_NODES) {
      float dv = dinv[v];
      dv_s[t] = dv;
      a_s[t] = dv * sx[v];
      c_s[t] = dv * sd[v];
      int b = batch[v];
      xr_s[t] = x[root[b]];
    } else {
      dv_s[t] = 0.f; a_s[t] = 0.f; c_s[t] = 0.f; xr_s[t] = 0.f;
    }
  }
  __syncthreads();
  for (int idx = t; idx < NPB8 * ZDIM; idx += 128) {
    int m = idx / ZDIM, j = idx - m * ZDIM;
    float val;
    if (j < HID)
      val = a_s[m] * wc[j] + c_s[m] * bcv[j] + bc1[j];
    else {
      int cc = j - HID;
      val = xr_s[m] * wv[cc] + bv[cc];
    }
    z[m][j] = val > 0.f ? val : 0.f;
  }
  __syncthreads();
  float acc[NPB8];
#pragma unroll
  for (int m = 0; m < NPB8; ++m) acc[m] = 0.f;
  int o = t;
  for (int j = 0; j < ZDIM; ++j) {
    float w = Wc2[j * 128 + o];
#pragma unroll
    for (int m = 0; m < NPB8; ++m) acc[m] += z[m][j] * w;
  }
#pragma unroll
  for (int m = 0; m < NPB8; ++m) {
    int v = v0 + m;
    if (v < N_NODES) hW2g[(size_t)v * 128 + o] = dv_s[m] * acc[m];
  }
}

// K9: conv2 gather (CSR) + relu + per-graph partial-sum flush (batch is sorted)
#define GNPB 16
__global__ __launch_bounds__(128) void k_conv2(
    const int* __restrict__ off, const int* __restrict__ csr,
    const float* __restrict__ hW2g, const float* __restrict__ dinv,
    const float* __restrict__ bc2, const int* __restrict__ batch,
    float* __restrict__ gsum) {
  int k = threadIdx.x;
  int v0 = blockIdx.x * GNPB;
  if (v0 >= N_NODES) return;
  int vend = v0 + GNPB;
  if (vend > N_NODES) vend = N_NODES;
  float bk = bc2[k];
  float local = 0.f;
  int cur_b = batch[v0];
  for (int v = v0; v < vend; ++v) {
    int b = batch[v];
    if (b != cur_b) {
      atomicAdd(&gsum[cur_b * 128 + k], local);
      local = 0.f;
      cur_b = b;
    }
    int o0 = off[v], o1 = off[v + 1];
    float acc = hW2g[(size_t)v * 128 + k];
    for (int i = o0; i < o1; ++i) {
      int s = csr[i];
      acc += hW2g[(size_t)s * 128 + k];
    }
    float val = dinv[v] * acc + bk;
    local += val > 0.f ? val : 0.f;
  }
  atomicAdd(&gsum[cur_b * 128 + k], local);
}

// K11: finalize — mean of relu(out2) half + closed-form out1[root] half
__global__ __launch_bounds__(128) void k_final(
    const float* __restrict__ gsum, const int* __restrict__ start,
    const int* __restrict__ root, const float* __restrict__ dinv,
    const float* __restrict__ sx, const float* __restrict__ sd,
    const float* __restrict__ wc, const float* __restrict__ bcv,
    const float* __restrict__ bc1, float* __restrict__ out) {
  int b = blockIdx.x, k = threadIdx.x;
  int c = start[b + 1] - start[b];
  float cnt = (c < 1) ? 1.f : (float)c;
  out[b * 256 + k] = gsum[b * 128 + k] / cnt;
  int r = root[b];
  float dr = dinv[r];
  float a = dr * sx[r], cc = dr * sd[r];
  out[b * 256 + 128 + k] = a * wc[k] + cc * bcv[k] + bc1[k];
}

extern "C" void kernel_launch(void* const* d_in, const int* in_sizes, int n_in,
                              void* d_out, int out_size, void* d_ws, size_t ws_size,
                              hipStream_t stream) {
  const float* x   = (const float*)d_in[0];
  const int* ei    = (const int*)d_in[1];
  const int* batch = (const int*)d_in[2];
  const int* root  = (const int*)d_in[3];
  const float* W1  = (const float*)d_in[4];
  const float* b1  = (const float*)d_in[5];
  const float* W2  = (const float*)d_in[6];
  const float* b2  = (const float*)d_in[7];
  const float* W3  = (const float*)d_in[8];
  const float* b3  = (const float*)d_in[9];
  const float* Wc1 = (const float*)d_in[10];
  const float* bc1 = (const float*)d_in[11];
  const float* Wc2 = (const float*)d_in[12];
  const float* bc2 = (const float*)d_in[13];
  float* out = (float*)d_out;

  const int* src = ei;            // edge_index[0]
  const int* dst = ei + N_EDGES;  // edge_index[1]

  // workspace carve-up (256B aligned)
  char* base = (char*)d_ws;
  size_t pos = 0;
  auto alloc = [&](size_t bytes) {
    size_t o = pos;
    pos = (pos + bytes + 255) & ~(size_t)255;
    return (void*)(base + o);
  };
  float* wv   = (float*)alloc(64 * 4);
  float* bv   = (float*)alloc(64 * 4);
  float* wc   = (float*)alloc(128 * 4);
  float* bcv  = (float*)alloc(128 * 4);
  float* dinv = (float*)alloc((size_t)N_NODES * 4);
  float* sx   = (float*)alloc((size_t)N_NODES * 4);
  float* sd   = (float*)alloc((size_t)N_NODES * 4);
  int* deg    = (int*)alloc((size_t)N_NODES * 4);
  int* cursor = (int*)alloc((size_t)N_NODES * 4);
  int* off    = (int*)alloc((size_t)(N_NODES + 1) * 4);
  int* bsum   = (int*)alloc(64 * 4);
  int* csr    = (int*)alloc((size_t)N_EDGES * 4);
  float* hW2g = (float*)alloc((size_t)N_NODES * 128 * 4);
  float* gsum = (float*)alloc((size_t)N_GRAPH * 128 * 4);
  int* start  = (int*)alloc((size_t)(N_GRAPH + 1) * 4);
  (void)ws_size; (void)in_sizes; (void)n_in; (void)out_size;

  const int TB = 256;
  int gN = (N_NODES + TB - 1) / TB;
  int gE = (N_EDGES + TB - 1) / TB;
  int nScanBlk = (N_NODES + 1023) / 1024;  // 40

  hipLaunchKernelGGL(k_prep, dim3(1), dim3(256), 0, stream,
                     W1, b1, W2, b2, W3, b3, Wc1, wv, bv, wc, bcv);
  hipLaunchKernelGGL(k_init, dim3(gN), dim3(TB), 0, stream, deg, cursor, gsum);
  hipLaunchKernelGGL(k_deg, dim3(gE), dim3(TB), 0, stream, dst, deg);
  hipLaunchKernelGGL(k_dinv, dim3(gN), dim3(TB), 0, stream, deg, dinv);
  hipLaunchKernelGGL(k_scanA, dim3(nScanBlk), dim3(256), 0, stream, deg, off, bsum);
  hipLaunchKernelGGL(k_scanB, dim3(1), dim3(64), 0, stream, bsum, off, nScanBlk);
  hipLaunchKernelGGL(k_scanC, dim3(gN), dim3(TB), 0, stream, off, bsum);
  hipLaunchKernelGGL(k_fill, dim3(gE), dim3(TB), 0, stream, src, dst, off, cursor, csr);
  hipLaunchKernelGGL(k_bounds, dim3(gN), dim3(TB), 0, stream, batch, start);
  hipLaunchKernelGGL(k_sxsd, dim3((N_NODES + 63) / 64), dim3(256), 0, stream,
                     off, csr, x, dinv, sx, sd);
  hipLaunchKernelGGL(k_mlp2, dim3((N_NODES + NPB8 - 1) / NPB8), dim3(128), 0, stream,
                     x, batch, root, dinv, sx, sd, wc, bcv, bc1, wv, bv, Wc2, hW2g);
  hipLaunchKernelGGL(k_conv2, dim3((N_NODES + GNPB - 1) / GNPB), dim3(128), 0, stream,
                     off, csr, hW2g, dinv, bc2, batch, gsum);
  hipLaunchKernelGGL(k_final, dim3(N_GRAPH), dim3(128), 0, stream,
                     gsum, start, root, dinv, sx, sd, wc, bcv, bc1, out);
}

// Round 3
// 176.687 us; speedup vs baseline: 2.8957x; 1.5102x over previous
//
#include <hip/hip_runtime.h>
#include <hip/hip_bf16.h>

#define N_NODES 40000
#define N_EDGES 640000
#define N_GRAPH 64
#define C_IN 64
#define HID 128
#define OUT 128
#define ZDIM 192   // HID + C_IN

__device__ __forceinline__ unsigned short f2bf(float f) {
  unsigned u = __float_as_uint(f);
  unsigned r = (u + 0x7FFFu + ((u >> 16) & 1u)) >> 16;
  return (unsigned short)r;
}

__device__ __forceinline__ void bf8_add(float* acc, uint4 r) {
  acc[0] += __uint_as_float(r.x << 16);
  acc[1] += __uint_as_float(r.x & 0xFFFF0000u);
  acc[2] += __uint_as_float(r.y << 16);
  acc[3] += __uint_as_float(r.y & 0xFFFF0000u);
  acc[4] += __uint_as_float(r.z << 16);
  acc[5] += __uint_as_float(r.z & 0xFFFF0000u);
  acc[6] += __uint_as_float(r.w << 16);
  acc[7] += __uint_as_float(r.w & 0xFFFF0000u);
}

// ---------------------------------------------------------------------------
// K1: collapse the affine chains.
__global__ __launch_bounds__(256) void k_prep(
    const float* __restrict__ W1, const float* __restrict__ b1,
    const float* __restrict__ W2, const float* __restrict__ b2,
    const float* __restrict__ W3, const float* __restrict__ b3,
    const float* __restrict__ Wc1,
    float* __restrict__ wv, float* __restrict__ bv,
    float* __restrict__ wc, float* __restrict__ bcv) {
  __shared__ float t1[256], u1[256], wv_s[64], bv_s[64];
  int t = threadIdx.x;
  float s1 = 0.f, s2 = 0.f;
  for (int j = 0; j < 64; ++j) {
    float w = W2[j * 256 + t];
    s1 += W1[j] * w;
    s2 += b1[j] * w;
  }
  t1[t] = s1;
  u1[t] = s2 + b2[t];
  __syncthreads();
  if (t < 64) {
    float a = 0.f, bb = 0.f;
    for (int k = 0; k < 256; ++k) {
      float w = W3[k * 64 + t];
      a += t1[k] * w;
      bb += u1[k] * w;
    }
    bb += b3[t];
    wv_s[t] = a; bv_s[t] = bb;
    wv[t] = a;  bv[t] = bb;
  }
  __syncthreads();
  if (t < 128) {
    float a = 0.f, bb = 0.f;
    for (int c = 0; c < 64; ++c) {
      float w = Wc1[c * 128 + t];
      a += wv_s[c] * w;
      bb += bv_s[c] * w;
    }
    wc[t] = a; bcv[t] = bb;
  }
}

// K2: init scratch + per-graph segment bounds (batch is sorted; no atomics)
__global__ void k_init(int* __restrict__ deg, int* __restrict__ cursor,
                       float* __restrict__ gsum,
                       const int* __restrict__ batch, int* __restrict__ start) {
  int i = blockIdx.x * blockDim.x + threadIdx.x;
  if (i < N_NODES) { deg[i] = 1; cursor[i] = 0; }
  if (i < N_GRAPH * OUT) gsum[i] = 0.f;
  if (i < N_NODES) {
    int bv = batch[i];
    if (i == 0) {
      for (int b = 0; b <= bv; ++b) start[b] = 0;
    } else {
      int bp = batch[i - 1];
      for (int b = bp + 1; b <= bv; ++b) start[b] = i;
    }
    if (i == N_NODES - 1) {
      for (int b = bv + 1; b <= N_GRAPH; ++b) start[b] = N_NODES;
    }
  }
}

// K3: in-degree (+1 self loop already in init)
__global__ void k_deg(const int* __restrict__ dst, int* __restrict__ deg) {
  int e = blockIdx.x * blockDim.x + threadIdx.x;
  if (e < N_EDGES) atomicAdd(&deg[dst[e]], 1);
}

// K6a: block scan of (deg-1) + dinv compute (fused)
__global__ __launch_bounds__(256) void k_scanA(const int* __restrict__ deg,
                                               int* __restrict__ off,
                                               int* __restrict__ bsum,
                                               float* __restrict__ dinv) {
  __shared__ int s[256];
  int t = threadIdx.x;
  int base = blockIdx.x * 1024;
  int vals[4];
  int loc = 0;
  for (int i = 0; i < 4; ++i) {
    int v = base + t * 4 + i;
    int d = 0;
    if (v < N_NODES) {
      int df = deg[v];
      d = df - 1;
      dinv[v] = 1.0f / sqrtf((float)df);
    }
    vals[i] = loc;
    loc += d;
  }
  s[t] = loc;
  __syncthreads();
  for (int ofs = 1; ofs < 256; ofs <<= 1) {
    int a = (t >= ofs) ? s[t - ofs] : 0;
    __syncthreads();
    s[t] += a;
    __syncthreads();
  }
  int texcl = s[t] - loc;
  for (int i = 0; i < 4; ++i) {
    int v = base + t * 4 + i;
    if (v < N_NODES) off[v] = texcl + vals[i];
  }
  if (t == 255) bsum[blockIdx.x] = s[255];
}

__global__ __launch_bounds__(64) void k_scanB(int* __restrict__ bsum,
                                              int* __restrict__ off, int nb) {
  __shared__ int s[64];
  int t = threadIdx.x;
  int v = (t < nb) ? bsum[t] : 0;
  s[t] = v;
  __syncthreads();
  for (int ofs = 1; ofs < 64; ofs <<= 1) {
    int a = (t >= ofs) ? s[t - ofs] : 0;
    __syncthreads();
    s[t] += a;
    __syncthreads();
  }
  if (t < nb) bsum[t] = s[t] - v;
  if (t == 63) off[N_NODES] = s[63];
}

__global__ void k_scanC(int* __restrict__ off, const int* __restrict__ bsum) {
  int v = blockIdx.x * blockDim.x + threadIdx.x;
  if (v < N_NODES) off[v] += bsum[v >> 10];
}

// K7: CSR fill (bucket by dst)
__global__ void k_fill(const int* __restrict__ src, const int* __restrict__ dst,
                       const int* __restrict__ off, int* __restrict__ cursor,
                       int* __restrict__ csr_src) {
  int e = blockIdx.x * blockDim.x + threadIdx.x;
  if (e < N_EDGES) {
    int d = dst[e];
    int p = atomicAdd(&cursor[d], 1);
    csr_src[off[d] + p] = src[e];
  }
}

// K5': conv1 scalar aggregates via CSR gather (no atomics).
__global__ __launch_bounds__(256) void k_sxsd(
    const int* __restrict__ off, const int* __restrict__ csr,
    const float* __restrict__ x, const float* __restrict__ dinv,
    float* __restrict__ sx, float* __restrict__ sd) {
  int t = threadIdx.x;
  int g = t >> 2;
  int l = t & 3;
  int v = blockIdx.x * 64 + g;
  if (v >= N_NODES) return;
  int o0 = off[v], o1 = off[v + 1];
  float ax = 0.f, ad = 0.f;
  for (int i = o0 + l; i < o1; i += 4) {
    int s = csr[i];
    float ds = dinv[s];
    ax += ds * x[s];
    ad += ds;
  }
  ax += __shfl_xor(ax, 1, 4); ad += __shfl_xor(ad, 1, 4);
  ax += __shfl_xor(ax, 2, 4); ad += __shfl_xor(ad, 2, 4);
  if (l == 0) {
    float dv = dinv[v];
    sx[v] = ax + dv * x[v];
    sd[v] = ad + dv;
  }
}

// K8: z[v] = relu(concat(out1[v], x1[root])) on the fly;
//     hW2g[v] = bf16( dinv[v] * (z[v] @ Wc2) )   [N,128] bf16
#define NPB 16
__global__ __launch_bounds__(128) void k_mlp2(
    const float* __restrict__ x, const int* __restrict__ batch,
    const int* __restrict__ root, const float* __restrict__ dinv,
    const float* __restrict__ sx, const float* __restrict__ sd,
    const float* __restrict__ wc, const float* __restrict__ bcv,
    const float* __restrict__ bc1, const float* __restrict__ wv,
    const float* __restrict__ bv, const float* __restrict__ Wc2,
    unsigned short* __restrict__ hW2g) {
  __shared__ float z[NPB][ZDIM];
  __shared__ float a_s[NPB], c_s[NPB], xr_s[NPB], dv_s[NPB];
  int t = threadIdx.x;
  int v0 = blockIdx.x * NPB;
  if (t < NPB) {
    int v = v0 + t;
    if (v < N_NODES) {
      float dv = dinv[v];
      dv_s[t] = dv;
      a_s[t] = dv * sx[v];
      c_s[t] = dv * sd[v];
      int b = batch[v];
      xr_s[t] = x[root[b]];
    } else {
      dv_s[t] = 0.f; a_s[t] = 0.f; c_s[t] = 0.f; xr_s[t] = 0.f;
    }
  }
  __syncthreads();
  for (int idx = t; idx < NPB * ZDIM; idx += 128) {
    int m = idx / ZDIM, j = idx - m * ZDIM;
    float val;
    if (j < HID)
      val = a_s[m] * wc[j] + c_s[m] * bcv[j] + bc1[j];
    else {
      int cc = j - HID;
      val = xr_s[m] * wv[cc] + bv[cc];
    }
    z[m][j] = val > 0.f ? val : 0.f;
  }
  __syncthreads();
  float acc[NPB];
#pragma unroll
  for (int m = 0; m < NPB; ++m) acc[m] = 0.f;
  int o = t;
  for (int j = 0; j < ZDIM; j += 4) {
    float w0 = Wc2[(j + 0) * 128 + o];
    float w1 = Wc2[(j + 1) * 128 + o];
    float w2 = Wc2[(j + 2) * 128 + o];
    float w3 = Wc2[(j + 3) * 128 + o];
#pragma unroll
    for (int m = 0; m < NPB; ++m) {
      float4 zv = *(const float4*)&z[m][j];
      acc[m] = fmaf(zv.x, w0, fmaf(zv.y, w1, fmaf(zv.z, w2, fmaf(zv.w, w3, acc[m]))));
    }
  }
#pragma unroll
  for (int m = 0; m < NPB; ++m) {
    int v = v0 + m;
    if (v < N_NODES) hW2g[(size_t)v * 128 + o] = f2bf(dv_s[m] * acc[m]);
  }
}

// K9: conv2 gather (CSR, bf16 rows, 16 lanes/row, unroll-4) + relu
//     + per-graph partial-sum flush (batch is sorted)
#define GNPB 16
__global__ __launch_bounds__(256) void k_conv2(
    const int* __restrict__ off, const int* __restrict__ csr,
    const uint4* __restrict__ hW2g,  // [N][16] uint4 = 128 bf16/row
    const float* __restrict__ dinv, const float* __restrict__ bc2,
    const int* __restrict__ batch, float* __restrict__ gsum) {
  __shared__ float s_out[GNPB][128];
  __shared__ int s_b[GNPB];
  int t = threadIdx.x;
  int g = t >> 4, l = t & 15;
  int v0 = blockIdx.x * GNPB;
  int v = v0 + g;
  if (t < GNPB) {
    int vv = v0 + t;
    s_b[t] = batch[vv < N_NODES ? vv : N_NODES - 1];
  }
  if (v < N_NODES) {
    const uint4* base = hW2g + l;
    float acc[8];
    {
      uint4 r = base[(size_t)v * 16];
      acc[0] = __uint_as_float(r.x << 16);
      acc[1] = __uint_as_float(r.x & 0xFFFF0000u);
      acc[2] = __uint_as_float(r.y << 16);
      acc[3] = __uint_as_float(r.y & 0xFFFF0000u);
      acc[4] = __uint_as_float(r.z << 16);
      acc[5] = __uint_as_float(r.z & 0xFFFF0000u);
      acc[6] = __uint_as_float(r.w << 16);
      acc[7] = __uint_as_float(r.w & 0xFFFF0000u);
    }
    int i = off[v], e = off[v + 1];
    for (; i + 4 <= e; i += 4) {
      int s0 = csr[i], s1 = csr[i + 1], s2 = csr[i + 2], s3 = csr[i + 3];
      uint4 r0 = base[(size_t)s0 * 16];
      uint4 r1 = base[(size_t)s1 * 16];
      uint4 r2 = base[(size_t)s2 * 16];
      uint4 r3 = base[(size_t)s3 * 16];
      bf8_add(acc, r0);
      bf8_add(acc, r1);
      bf8_add(acc, r2);
      bf8_add(acc, r3);
    }
    for (; i < e; ++i) bf8_add(acc, base[(size_t)csr[i] * 16]);
    float dv = dinv[v];
#pragma unroll
    for (int j = 0; j < 8; ++j) {
      float val = dv * acc[j] + bc2[l * 8 + j];
      s_out[g][l * 8 + j] = val > 0.f ? val : 0.f;
    }
  } else {
#pragma unroll
    for (int j = 0; j < 8; ++j) s_out[g][l * 8 + j] = 0.f;
  }
  __syncthreads();
  if (t < 128) {
    int k = t;
    float local = 0.f;
    int cur = s_b[0];
    for (int m = 0; m < GNPB; ++m) {
      int b = s_b[m];
      if (b != cur) {
        atomicAdd(&gsum[cur * 128 + k], local);
        local = 0.f;
        cur = b;
      }
      local += s_out[m][k];
    }
    atomicAdd(&gsum[cur * 128 + k], local);
  }
}

// K11: finalize — mean of relu(out2) half + closed-form out1[root] half
__global__ __launch_bounds__(128) void k_final(
    const float* __restrict__ gsum, const int* __restrict__ start,
    const int* __restrict__ root, const float* __restrict__ dinv,
    const float* __restrict__ sx, const float* __restrict__ sd,
    const float* __restrict__ wc, const float* __restrict__ bcv,
    const float* __restrict__ bc1, float* __restrict__ out) {
  int b = blockIdx.x, k = threadIdx.x;
  int c = start[b + 1] - start[b];
  float cnt = (c < 1) ? 1.f : (float)c;
  out[b * 256 + k] = gsum[b * 128 + k] / cnt;
  int r = root[b];
  float dr = dinv[r];
  float a = dr * sx[r], cc = dr * sd[r];
  out[b * 256 + 128 + k] = a * wc[k] + cc * bcv[k] + bc1[k];
}

extern "C" void kernel_launch(void* const* d_in, const int* in_sizes, int n_in,
                              void* d_out, int out_size, void* d_ws, size_t ws_size,
                              hipStream_t stream) {
  const float* x   = (const float*)d_in[0];
  const int* ei    = (const int*)d_in[1];
  const int* batch = (const int*)d_in[2];
  const int* root  = (const int*)d_in[3];
  const float* W1  = (const float*)d_in[4];
  const float* b1  = (const float*)d_in[5];
  const float* W2  = (const float*)d_in[6];
  const float* b2  = (const float*)d_in[7];
  const float* W3  = (const float*)d_in[8];
  const float* b3  = (const float*)d_in[9];
  const float* Wc1 = (const float*)d_in[10];
  const float* bc1 = (const float*)d_in[11];
  const float* Wc2 = (const float*)d_in[12];
  const float* bc2 = (const float*)d_in[13];
  float* out = (float*)d_out;

  const int* src = ei;            // edge_index[0]
  const int* dst = ei + N_EDGES;  // edge_index[1]

  char* base = (char*)d_ws;
  size_t pos = 0;
  auto alloc = [&](size_t bytes) {
    size_t o = pos;
    pos = (pos + bytes + 255) & ~(size_t)255;
    return (void*)(base + o);
  };
  float* wv   = (float*)alloc(64 * 4);
  float* bv   = (float*)alloc(64 * 4);
  float* wc   = (float*)alloc(128 * 4);
  float* bcv  = (float*)alloc(128 * 4);
  float* dinv = (float*)alloc((size_t)N_NODES * 4);
  float* sx   = (float*)alloc((size_t)N_NODES * 4);
  float* sd   = (float*)alloc((size_t)N_NODES * 4);
  int* deg    = (int*)alloc((size_t)N_NODES * 4);
  int* cursor = (int*)alloc((size_t)N_NODES * 4);
  int* off    = (int*)alloc((size_t)(N_NODES + 1) * 4);
  int* bsum   = (int*)alloc(64 * 4);
  int* csr    = (int*)alloc((size_t)N_EDGES * 4);
  unsigned short* hW2g = (unsigned short*)alloc((size_t)N_NODES * 128 * 2);
  float* gsum = (float*)alloc((size_t)N_GRAPH * 128 * 4);
  int* start  = (int*)alloc((size_t)(N_GRAPH + 1) * 4);
  (void)ws_size; (void)in_sizes; (void)n_in; (void)out_size;

  const int TB = 256;
  int gN = (N_NODES + TB - 1) / TB;
  int gE = (N_EDGES + TB - 1) / TB;
  int nScanBlk = (N_NODES + 1023) / 1024;  // 40

  hipLaunchKernelGGL(k_prep, dim3(1), dim3(256), 0, stream,
                     W1, b1, W2, b2, W3, b3, Wc1, wv, bv, wc, bcv);
  hipLaunchKernelGGL(k_init, dim3(gN), dim3(TB), 0, stream, deg, cursor, gsum, batch, start);
  hipLaunchKernelGGL(k_deg, dim3(gE), dim3(TB), 0, stream, dst, deg);
  hipLaunchKernelGGL(k_scanA, dim3(nScanBlk), dim3(256), 0, stream, deg, off, bsum, dinv);
  hipLaunchKernelGGL(k_scanB, dim3(1), dim3(64), 0, stream, bsum, off, nScanBlk);
  hipLaunchKernelGGL(k_scanC, dim3(gN), dim3(TB), 0, stream, off, bsum);
  hipLaunchKernelGGL(k_fill, dim3(gE), dim3(TB), 0, stream, src, dst, off, cursor, csr);
  hipLaunchKernelGGL(k_sxsd, dim3((N_NODES + 63) / 64), dim3(256), 0, stream,
                     off, csr, x, dinv, sx, sd);
  hipLaunchKernelGGL(k_mlp2, dim3((N_NODES + NPB - 1) / NPB), dim3(128), 0, stream,
                     x, batch, root, dinv, sx, sd, wc, bcv, bc1, wv, bv, Wc2, hW2g);
  hipLaunchKernelGGL(k_conv2, dim3((N_NODES + GNPB - 1) / GNPB), dim3(256), 0, stream,
                     off, csr, (const uint4*)hW2g, dinv, bc2, batch, gsum);
  hipLaunchKernelGGL(k_final, dim3(N_GRAPH), dim3(128), 0, stream,
                     gsum, start, root, dinv, sx, sd, wc, bcv, bc1, out);
}

// Round 4
// 157.937 us; speedup vs baseline: 3.2395x; 1.1187x over previous
//
#include <hip/hip_runtime.h>
#include <hip/hip_bf16.h>

#define N_NODES 40000
#define N_EDGES 640000
#define N_GRAPH 64
#define C_IN 64
#define HID 128
#define OUT 128
#define ZDIM 192   // HID + C_IN
#define ZPAD 200   // padded K stride (400 B: 2-way LDS bank alias = free)

typedef __bf16 bf16x8 __attribute__((ext_vector_type(8)));
typedef float  f32x4  __attribute__((ext_vector_type(4)));

__device__ __forceinline__ unsigned short f2bf(float f) {
  unsigned u = __float_as_uint(f);
  unsigned r = (u + 0x7FFFu + ((u >> 16) & 1u)) >> 16;
  return (unsigned short)r;
}

__device__ __forceinline__ void bf8_add(float* acc, uint4 r) {
  acc[0] += __uint_as_float(r.x << 16);
  acc[1] += __uint_as_float(r.x & 0xFFFF0000u);
  acc[2] += __uint_as_float(r.y << 16);
  acc[3] += __uint_as_float(r.y & 0xFFFF0000u);
  acc[4] += __uint_as_float(r.z << 16);
  acc[5] += __uint_as_float(r.z & 0xFFFF0000u);
  acc[6] += __uint_as_float(r.w << 16);
  acc[7] += __uint_as_float(r.w & 0xFFFF0000u);
}

// ---------------------------------------------------------------------------
// K1: collapse the affine chains.
__global__ __launch_bounds__(256) void k_prep(
    const float* __restrict__ W1, const float* __restrict__ b1,
    const float* __restrict__ W2, const float* __restrict__ b2,
    const float* __restrict__ W3, const float* __restrict__ b3,
    const float* __restrict__ Wc1,
    float* __restrict__ wv, float* __restrict__ bv,
    float* __restrict__ wc, float* __restrict__ bcv) {
  __shared__ float t1[256], u1[256], wv_s[64], bv_s[64];
  int t = threadIdx.x;
  float s1 = 0.f, s2 = 0.f;
  for (int j = 0; j < 64; ++j) {
    float w = W2[j * 256 + t];
    s1 += W1[j] * w;
    s2 += b1[j] * w;
  }
  t1[t] = s1;
  u1[t] = s2 + b2[t];
  __syncthreads();
  if (t < 64) {
    float a = 0.f, bb = 0.f;
    for (int k = 0; k < 256; ++k) {
      float w = W3[k * 64 + t];
      a += t1[k] * w;
      bb += u1[k] * w;
    }
    bb += b3[t];
    wv_s[t] = a; bv_s[t] = bb;
    wv[t] = a;  bv[t] = bb;
  }
  __syncthreads();
  if (t < 128) {
    float a = 0.f, bb = 0.f;
    for (int c = 0; c < 64; ++c) {
      float w = Wc1[c * 128 + t];
      a += wv_s[c] * w;
      bb += bv_s[c] * w;
    }
    wc[t] = a; bcv[t] = bb;
  }
}

// K2: init scratch + per-graph segment bounds (batch is sorted; no atomics)
__global__ void k_init(int* __restrict__ deg, int* __restrict__ cursor,
                       float* __restrict__ gsum,
                       const int* __restrict__ batch, int* __restrict__ start) {
  int i = blockIdx.x * blockDim.x + threadIdx.x;
  if (i < N_NODES) { deg[i] = 1; cursor[i] = 0; }
  if (i < N_GRAPH * OUT) gsum[i] = 0.f;
  if (i < N_NODES) {
    int bv = batch[i];
    if (i == 0) {
      for (int b = 0; b <= bv; ++b) start[b] = 0;
    } else {
      int bp = batch[i - 1];
      for (int b = bp + 1; b <= bv; ++b) start[b] = i;
    }
    if (i == N_NODES - 1) {
      for (int b = bv + 1; b <= N_GRAPH; ++b) start[b] = N_NODES;
    }
  }
}

// K3: in-degree (+1 self loop already in init)
__global__ void k_deg(const int* __restrict__ dst, int* __restrict__ deg) {
  int e = blockIdx.x * blockDim.x + threadIdx.x;
  if (e < N_EDGES) atomicAdd(&deg[dst[e]], 1);
}

// K6a: block scan of (deg-1) + dinv compute (fused)
__global__ __launch_bounds__(256) void k_scanA(const int* __restrict__ deg,
                                               int* __restrict__ off,
                                               int* __restrict__ bsum,
                                               float* __restrict__ dinv) {
  __shared__ int s[256];
  int t = threadIdx.x;
  int base = blockIdx.x * 1024;
  int vals[4];
  int loc = 0;
  for (int i = 0; i < 4; ++i) {
    int v = base + t * 4 + i;
    int d = 0;
    if (v < N_NODES) {
      int df = deg[v];
      d = df - 1;
      dinv[v] = 1.0f / sqrtf((float)df);
    }
    vals[i] = loc;
    loc += d;
  }
  s[t] = loc;
  __syncthreads();
  for (int ofs = 1; ofs < 256; ofs <<= 1) {
    int a = (t >= ofs) ? s[t - ofs] : 0;
    __syncthreads();
    s[t] += a;
    __syncthreads();
  }
  int texcl = s[t] - loc;
  for (int i = 0; i < 4; ++i) {
    int v = base + t * 4 + i;
    if (v < N_NODES) off[v] = texcl + vals[i];
  }
  if (t == 255) bsum[blockIdx.x] = s[255];
}

__global__ __launch_bounds__(64) void k_scanB(int* __restrict__ bsum,
                                              int* __restrict__ off, int nb) {
  __shared__ int s[64];
  int t = threadIdx.x;
  int v = (t < nb) ? bsum[t] : 0;
  s[t] = v;
  __syncthreads();
  for (int ofs = 1; ofs < 64; ofs <<= 1) {
    int a = (t >= ofs) ? s[t - ofs] : 0;
    __syncthreads();
    s[t] += a;
    __syncthreads();
  }
  if (t < nb) bsum[t] = s[t] - v;
  if (t == 63) off[N_NODES] = s[63];
}

__global__ void k_scanC(int* __restrict__ off, const int* __restrict__ bsum) {
  int v = blockIdx.x * blockDim.x + threadIdx.x;
  if (v < N_NODES) off[v] += bsum[v >> 10];
}

// K7: CSR fill (bucket by dst)
__global__ void k_fill(const int* __restrict__ src, const int* __restrict__ dst,
                       const int* __restrict__ off, int* __restrict__ cursor,
                       int* __restrict__ csr_src) {
  int e = blockIdx.x * blockDim.x + threadIdx.x;
  if (e < N_EDGES) {
    int d = dst[e];
    int p = atomicAdd(&cursor[d], 1);
    csr_src[off[d] + p] = src[e];
  }
}

// K5': conv1 scalar aggregates via CSR gather (no atomics).
__global__ __launch_bounds__(256) void k_sxsd(
    const int* __restrict__ off, const int* __restrict__ csr,
    const float* __restrict__ x, const float* __restrict__ dinv,
    float* __restrict__ sx, float* __restrict__ sd) {
  int t = threadIdx.x;
  int g = t >> 2;
  int l = t & 3;
  int v = blockIdx.x * 64 + g;
  if (v >= N_NODES) return;
  int o0 = off[v], o1 = off[v + 1];
  float ax = 0.f, ad = 0.f;
  for (int i = o0 + l; i < o1; i += 4) {
    int s = csr[i];
    float ds = dinv[s];
    ax += ds * x[s];
    ad += ds;
  }
  ax += __shfl_xor(ax, 1, 4); ad += __shfl_xor(ad, 1, 4);
  ax += __shfl_xor(ax, 2, 4); ad += __shfl_xor(ad, 2, 4);
  if (l == 0) {
    float dv = dinv[v];
    sx[v] = ax + dv * x[v];
    sd[v] = ad + dv;
  }
}

// K8 (MFMA): z[v] = relu(concat(out1[v], x1[root])) built in LDS (bf16);
//            hW2g[v] = bf16( dinv[v] * (z[v] @ Wc2) ) via mfma_f32_16x16x32_bf16.
// Block: 256 thr = 4 waves, 64 nodes. Wave w: rows w*16..w*16+15, all 128 cols.
__global__ __launch_bounds__(256) void k_mlp2(
    const float* __restrict__ x, const int* __restrict__ batch,
    const int* __restrict__ root, const float* __restrict__ dinv,
    const float* __restrict__ sx, const float* __restrict__ sd,
    const float* __restrict__ wc, const float* __restrict__ bcv,
    const float* __restrict__ bc1, const float* __restrict__ wv,
    const float* __restrict__ bv, const float* __restrict__ Wc2,
    unsigned short* __restrict__ hW2g) {
  __shared__ __align__(16) __bf16 wt[128][ZPAD];  // Wc2^T [col][k]  (50 KB)
  __shared__ __align__(16) __bf16 zs[64][ZPAD];   // z rows          (25.6 KB)
  __shared__ float s_dv[64], s_a[64], s_c[64], s_xr[64];
  int t = threadIdx.x;
  int v0 = blockIdx.x * 64;

  // stage Wc2^T (bf16)
  for (int idx = t; idx < ZDIM * 128; idx += 256) {
    int k = idx >> 7, col = idx & 127;
    wt[col][k] = (__bf16)Wc2[idx];
  }
  // per-node scalars
  if (t < 64) {
    int v = v0 + t;
    float dv = dinv[v];
    s_dv[t] = dv;
    s_a[t] = dv * sx[v];
    s_c[t] = dv * sd[v];
    s_xr[t] = x[root[batch[v]]];
  }
  __syncthreads();
  // build z rows in bf16
  for (int idx = t; idx < 64 * ZDIM; idx += 256) {
    int r = idx / ZDIM, j = idx - r * ZDIM;
    float val;
    if (j < HID)
      val = s_a[r] * wc[j] + s_c[r] * bcv[j] + bc1[j];
    else {
      int cc = j - HID;
      val = s_xr[r] * wv[cc] + bv[cc];
    }
    zs[r][j] = (__bf16)(val > 0.f ? val : 0.f);
  }
  __syncthreads();

  int w = t >> 6, l = t & 63;
  int rb = w * 16;                 // wave's row base
  int lr = l & 15, lg = l >> 4;    // lane row/col index, k-group

  // hoist A-fragments (reused across all 8 col-tiles)
  bf16x8 af[6];
#pragma unroll
  for (int kk = 0; kk < 6; ++kk)
    af[kk] = *reinterpret_cast<const bf16x8*>(&zs[rb + lr][kk * 32 + lg * 8]);

  // per-row dinv for the D-tile rows this lane owns: row = lg*4 + reg
  float dvr[4];
#pragma unroll
  for (int reg = 0; reg < 4; ++reg) dvr[reg] = s_dv[rb + lg * 4 + reg];

#pragma unroll
  for (int ct = 0; ct < 8; ++ct) {
    f32x4 acc = {0.f, 0.f, 0.f, 0.f};
#pragma unroll
    for (int kk = 0; kk < 6; ++kk) {
      bf16x8 bf = *reinterpret_cast<const bf16x8*>(&wt[ct * 16 + lr][kk * 32 + lg * 8]);
      acc = __builtin_amdgcn_mfma_f32_16x16x32_bf16(af[kk], bf, acc, 0, 0, 0);
    }
#pragma unroll
    for (int reg = 0; reg < 4; ++reg) {
      int v = v0 + rb + lg * 4 + reg;
      hW2g[(size_t)v * 128 + ct * 16 + lr] = f2bf(dvr[reg] * acc[reg]);
    }
  }
}

// K9: conv2 gather (CSR, bf16 rows, 16 lanes/row, unroll-4) + relu
//     + per-graph partial-sum flush (batch is sorted)
#define GNPB 16
__global__ __launch_bounds__(256) void k_conv2(
    const int* __restrict__ off, const int* __restrict__ csr,
    const uint4* __restrict__ hW2g,  // [N][16] uint4 = 128 bf16/row
    const float* __restrict__ dinv, const float* __restrict__ bc2,
    const int* __restrict__ batch, float* __restrict__ gsum) {
  __shared__ float s_out[GNPB][128];
  __shared__ int s_b[GNPB];
  int t = threadIdx.x;
  int g = t >> 4, l = t & 15;
  int v0 = blockIdx.x * GNPB;
  int v = v0 + g;
  if (t < GNPB) {
    int vv = v0 + t;
    s_b[t] = batch[vv < N_NODES ? vv : N_NODES - 1];
  }
  if (v < N_NODES) {
    const uint4* base = hW2g + l;
    float acc[8];
    {
      uint4 r = base[(size_t)v * 16];
      acc[0] = __uint_as_float(r.x << 16);
      acc[1] = __uint_as_float(r.x & 0xFFFF0000u);
      acc[2] = __uint_as_float(r.y << 16);
      acc[3] = __uint_as_float(r.y & 0xFFFF0000u);
      acc[4] = __uint_as_float(r.z << 16);
      acc[5] = __uint_as_float(r.z & 0xFFFF0000u);
      acc[6] = __uint_as_float(r.w << 16);
      acc[7] = __uint_as_float(r.w & 0xFFFF0000u);
    }
    int i = off[v], e = off[v + 1];
    for (; i + 4 <= e; i += 4) {
      int s0 = csr[i], s1 = csr[i + 1], s2 = csr[i + 2], s3 = csr[i + 3];
      uint4 r0 = base[(size_t)s0 * 16];
      uint4 r1 = base[(size_t)s1 * 16];
      uint4 r2 = base[(size_t)s2 * 16];
      uint4 r3 = base[(size_t)s3 * 16];
      bf8_add(acc, r0);
      bf8_add(acc, r1);
      bf8_add(acc, r2);
      bf8_add(acc, r3);
    }
    for (; i < e; ++i) bf8_add(acc, base[(size_t)csr[i] * 16]);
    float dv = dinv[v];
#pragma unroll
    for (int j = 0; j < 8; ++j) {
      float val = dv * acc[j] + bc2[l * 8 + j];
      s_out[g][l * 8 + j] = val > 0.f ? val : 0.f;
    }
  } else {
#pragma unroll
    for (int j = 0; j < 8; ++j) s_out[g][l * 8 + j] = 0.f;
  }
  __syncthreads();
  if (t < 128) {
    int k = t;
    float local = 0.f;
    int cur = s_b[0];
    for (int m = 0; m < GNPB; ++m) {
      int b = s_b[m];
      if (b != cur) {
        atomicAdd(&gsum[cur * 128 + k], local);
        local = 0.f;
        cur = b;
      }
      local += s_out[m][k];
    }
    atomicAdd(&gsum[cur * 128 + k], local);
  }
}

// K11: finalize — mean of relu(out2) half + closed-form out1[root] half
__global__ __launch_bounds__(128) void k_final(
    const float* __restrict__ gsum, const int* __restrict__ start,
    const int* __restrict__ root, const float* __restrict__ dinv,
    const float* __restrict__ sx, const float* __restrict__ sd,
    const float* __restrict__ wc, const float* __restrict__ bcv,
    const float* __restrict__ bc1, float* __restrict__ out) {
  int b = blockIdx.x, k = threadIdx.x;
  int c = start[b + 1] - start[b];
  float cnt = (c < 1) ? 1.f : (float)c;
  out[b * 256 + k] = gsum[b * 128 + k] / cnt;
  int r = root[b];
  float dr = dinv[r];
  float a = dr * sx[r], cc = dr * sd[r];
  out[b * 256 + 128 + k] = a * wc[k] + cc * bcv[k] + bc1[k];
}

extern "C" void kernel_launch(void* const* d_in, const int* in_sizes, int n_in,
                              void* d_out, int out_size, void* d_ws, size_t ws_size,
                              hipStream_t stream) {
  const float* x   = (const float*)d_in[0];
  const int* ei    = (const int*)d_in[1];
  const int* batch = (const int*)d_in[2];
  const int* root  = (const int*)d_in[3];
  const float* W1  = (const float*)d_in[4];
  const float* b1  = (const float*)d_in[5];
  const float* W2  = (const float*)d_in[6];
  const float* b2  = (const float*)d_in[7];
  const float* W3  = (const float*)d_in[8];
  const float* b3  = (const float*)d_in[9];
  const float* Wc1 = (const float*)d_in[10];
  const float* bc1 = (const float*)d_in[11];
  const float* Wc2 = (const float*)d_in[12];
  const float* bc2 = (const float*)d_in[13];
  float* out = (float*)d_out;

  const int* src = ei;            // edge_index[0]
  const int* dst = ei + N_EDGES;  // edge_index[1]

  char* base = (char*)d_ws;
  size_t pos = 0;
  auto alloc = [&](size_t bytes) {
    size_t o = pos;
    pos = (pos + bytes + 255) & ~(size_t)255;
    return (void*)(base + o);
  };
  float* wv   = (float*)alloc(64 * 4);
  float* bv   = (float*)alloc(64 * 4);
  float* wc   = (float*)alloc(128 * 4);
  float* bcv  = (float*)alloc(128 * 4);
  float* dinv = (float*)alloc((size_t)N_NODES * 4);
  float* sx   = (float*)alloc((size_t)N_NODES * 4);
  float* sd   = (float*)alloc((size_t)N_NODES * 4);
  int* deg    = (int*)alloc((size_t)N_NODES * 4);
  int* cursor = (int*)alloc((size_t)N_NODES * 4);
  int* off    = (int*)alloc((size_t)(N_NODES + 1) * 4);
  int* bsum   = (int*)alloc(64 * 4);
  int* csr    = (int*)alloc((size_t)N_EDGES * 4);
  unsigned short* hW2g = (unsigned short*)alloc((size_t)N_NODES * 128 * 2);
  float* gsum = (float*)alloc((size_t)N_GRAPH * 128 * 4);
  int* start  = (int*)alloc((size_t)(N_GRAPH + 1) * 4);
  (void)ws_size; (void)in_sizes; (void)n_in; (void)out_size;

  const int TB = 256;
  int gN = (N_NODES + TB - 1) / TB;
  int gE = (N_EDGES + TB - 1) / TB;
  int nScanBlk = (N_NODES + 1023) / 1024;  // 40

  hipLaunchKernelGGL(k_prep, dim3(1), dim3(256), 0, stream,
                     W1, b1, W2, b2, W3, b3, Wc1, wv, bv, wc, bcv);
  hipLaunchKernelGGL(k_init, dim3(gN), dim3(TB), 0, stream, deg, cursor, gsum, batch, start);
  hipLaunchKernelGGL(k_deg, dim3(gE), dim3(TB), 0, stream, dst, deg);
  hipLaunchKernelGGL(k_scanA, dim3(nScanBlk), dim3(256), 0, stream, deg, off, bsum, dinv);
  hipLaunchKernelGGL(k_scanB, dim3(1), dim3(64), 0, stream, bsum, off, nScanBlk);
  hipLaunchKernelGGL(k_scanC, dim3(gN), dim3(TB), 0, stream, off, bsum);
  hipLaunchKernelGGL(k_fill, dim3(gE), dim3(TB), 0, stream, src, dst, off, cursor, csr);
  hipLaunchKernelGGL(k_sxsd, dim3((N_NODES + 63) / 64), dim3(256), 0, stream,
                     off, csr, x, dinv, sx, sd);
  hipLaunchKernelGGL(k_mlp2, dim3(N_NODES / 64), dim3(256), 0, stream,
                     x, batch, root, dinv, sx, sd, wc, bcv, bc1, wv, bv, Wc2, hW2g);
  hipLaunchKernelGGL(k_conv2, dim3((N_NODES + GNPB - 1) / GNPB), dim3(256), 0, stream,
                     off, csr, (const uint4*)hW2g, dinv, bc2, batch, gsum);
  hipLaunchKernelGGL(k_final, dim3(N_GRAPH), dim3(128), 0, stream,
                     gsum, start, root, dinv, sx, sd, wc, bcv, bc1, out);
}

// Round 5
// 154.063 us; speedup vs baseline: 3.3209x; 1.0251x over previous
//
#include <hip/hip_runtime.h>
#include <hip/hip_bf16.h>

#define N_NODES 40000
#define N_EDGES 640000
#define N_GRAPH 64
#define C_IN 64
#define HID 128
#define OUT 128
#define ZDIM 192   // HID + C_IN
#define ZPAD 200   // padded K stride (400 B: 2-way LDS bank alias = free)

typedef __bf16 bf16x8 __attribute__((ext_vector_type(8)));
typedef float  f32x4  __attribute__((ext_vector_type(4)));

__device__ __forceinline__ unsigned short f2bf(float f) {
  unsigned u = __float_as_uint(f);
  unsigned r = (u + 0x7FFFu + ((u >> 16) & 1u)) >> 16;
  return (unsigned short)r;
}

__device__ __forceinline__ void bf8_add(float* acc, uint4 r) {
  acc[0] += __uint_as_float(r.x << 16);
  acc[1] += __uint_as_float(r.x & 0xFFFF0000u);
  acc[2] += __uint_as_float(r.y << 16);
  acc[3] += __uint_as_float(r.y & 0xFFFF0000u);
  acc[4] += __uint_as_float(r.z << 16);
  acc[5] += __uint_as_float(r.z & 0xFFFF0000u);
  acc[6] += __uint_as_float(r.w << 16);
  acc[7] += __uint_as_float(r.w & 0xFFFF0000u);
}

// ---------------------------------------------------------------------------
// K1: collapse the affine chains.
__global__ __launch_bounds__(256) void k_prep(
    const float* __restrict__ W1, const float* __restrict__ b1,
    const float* __restrict__ W2, const float* __restrict__ b2,
    const float* __restrict__ W3, const float* __restrict__ b3,
    const float* __restrict__ Wc1,
    float* __restrict__ wv, float* __restrict__ bv,
    float* __restrict__ wc, float* __restrict__ bcv) {
  __shared__ float t1[256], u1[256], wv_s[64], bv_s[64];
  int t = threadIdx.x;
  float s1 = 0.f, s2 = 0.f;
  for (int j = 0; j < 64; ++j) {
    float w = W2[j * 256 + t];
    s1 += W1[j] * w;
    s2 += b1[j] * w;
  }
  t1[t] = s1;
  u1[t] = s2 + b2[t];
  __syncthreads();
  if (t < 64) {
    float a = 0.f, bb = 0.f;
    for (int k = 0; k < 256; ++k) {
      float w = W3[k * 64 + t];
      a += t1[k] * w;
      bb += u1[k] * w;
    }
    bb += b3[t];
    wv_s[t] = a; bv_s[t] = bb;
    wv[t] = a;  bv[t] = bb;
  }
  __syncthreads();
  if (t < 128) {
    float a = 0.f, bb = 0.f;
    for (int c = 0; c < 64; ++c) {
      float w = Wc1[c * 128 + t];
      a += wv_s[c] * w;
      bb += bv_s[c] * w;
    }
    wc[t] = a; bcv[t] = bb;
  }
}

// K3: raw in-degree (deg memset to 0; self-loop folded as deg+1 downstream)
__global__ void k_deg(const int* __restrict__ dst, int* __restrict__ deg) {
  int e = blockIdx.x * blockDim.x + threadIdx.x;
  if (e < N_EDGES) atomicAdd(&deg[dst[e]], 1);
}

// K6a: block scan of raw deg -> CSR offsets, + dinv, + per-graph segment bounds
__global__ __launch_bounds__(256) void k_scanA(const int* __restrict__ deg,
                                               int* __restrict__ off,
                                               int* __restrict__ bsum,
                                               float* __restrict__ dinv,
                                               const int* __restrict__ batch,
                                               int* __restrict__ start) {
  __shared__ int s[256];
  int t = threadIdx.x;
  int base = blockIdx.x * 1024;
  int vals[4];
  int loc = 0;
  for (int i = 0; i < 4; ++i) {
    int v = base + t * 4 + i;
    int d = 0;
    if (v < N_NODES) {
      d = deg[v];  // raw in-degree
      dinv[v] = 1.0f / sqrtf((float)(d + 1));
      // segment bounds (batch sorted)
      int bv = batch[v];
      if (v == 0) {
        for (int b = 0; b <= bv; ++b) start[b] = 0;
      } else {
        int bp = batch[v - 1];
        for (int b = bp + 1; b <= bv; ++b) start[b] = v;
      }
      if (v == N_NODES - 1) {
        for (int b = bv + 1; b <= N_GRAPH; ++b) start[b] = N_NODES;
      }
    }
    vals[i] = loc;
    loc += d;
  }
  s[t] = loc;
  __syncthreads();
  for (int ofs = 1; ofs < 256; ofs <<= 1) {
    int a = (t >= ofs) ? s[t - ofs] : 0;
    __syncthreads();
    s[t] += a;
    __syncthreads();
  }
  int texcl = s[t] - loc;
  for (int i = 0; i < 4; ++i) {
    int v = base + t * 4 + i;
    if (v < N_NODES) off[v] = texcl + vals[i];
  }
  if (t == 255) bsum[blockIdx.x] = s[255];
}

__global__ __launch_bounds__(64) void k_scanB(int* __restrict__ bsum,
                                              int* __restrict__ off, int nb) {
  __shared__ int s[64];
  int t = threadIdx.x;
  int v = (t < nb) ? bsum[t] : 0;
  s[t] = v;
  __syncthreads();
  for (int ofs = 1; ofs < 64; ofs <<= 1) {
    int a = (t >= ofs) ? s[t - ofs] : 0;
    __syncthreads();
    s[t] += a;
    __syncthreads();
  }
  if (t < nb) bsum[t] = s[t] - v;
  if (t == 63) off[N_NODES] = s[63];
}

// K7: CSR fill (bucket by dst); final offset = off[d] + bsum[d>>10]
__global__ void k_fill(const int* __restrict__ src, const int* __restrict__ dst,
                       const int* __restrict__ off, const int* __restrict__ bsum,
                       int* __restrict__ cursor, int* __restrict__ csr_src) {
  int e = blockIdx.x * blockDim.x + threadIdx.x;
  if (e < N_EDGES) {
    int d = dst[e];
    int p = atomicAdd(&cursor[d], 1);
    csr_src[off[d] + bsum[d >> 10] + p] = src[e];
  }
}

// K8 (MFMA, fused sxsd): per block = 64 nodes, 256 thr = 4 waves.
// Phase 1: gather sx/sd via CSR (4 lanes/node) -> LDS + global (for k_final).
// Phase 2: z rows (bf16) in LDS; Phase 3: z @ Wc2 via mfma_f32_16x16x32_bf16.
__global__ __launch_bounds__(256) void k_mlp2(
    const float* __restrict__ x, const int* __restrict__ batch,
    const int* __restrict__ root, const float* __restrict__ dinv,
    const int* __restrict__ off, const int* __restrict__ bsum,
    const int* __restrict__ csr,
    const float* __restrict__ wc, const float* __restrict__ bcv,
    const float* __restrict__ bc1, const float* __restrict__ wv,
    const float* __restrict__ bv, const float* __restrict__ Wc2,
    float* __restrict__ sx, float* __restrict__ sd,
    unsigned short* __restrict__ hW2g) {
  __shared__ __align__(16) __bf16 wt[128][ZPAD];  // Wc2^T [col][k]
  __shared__ __align__(16) __bf16 zs[64][ZPAD];   // z rows
  __shared__ float s_dv[64], s_a[64], s_c[64], s_xr[64];
  int t = threadIdx.x;
  int v0 = blockIdx.x * 64;

  // stage Wc2^T (bf16)
  for (int idx = t; idx < ZDIM * 128; idx += 256) {
    int k = idx >> 7, col = idx & 127;
    wt[col][k] = (__bf16)Wc2[idx];
  }

  // fused sxsd gather: 4 lanes per node
  {
    int g4 = t >> 2, l4 = t & 3;
    int v = v0 + g4;
    int o0 = off[v] + bsum[v >> 10];
    int o1 = (v + 1 < N_NODES) ? off[v + 1] + bsum[(v + 1) >> 10] : off[N_NODES];
    float ax = 0.f, ad = 0.f;
    for (int i = o0 + l4; i < o1; i += 4) {
      int s = csr[i];
      float ds = dinv[s];
      ax += ds * x[s];
      ad += ds;
    }
    ax += __shfl_xor(ax, 1, 4); ad += __shfl_xor(ad, 1, 4);
    ax += __shfl_xor(ax, 2, 4); ad += __shfl_xor(ad, 2, 4);
    if (l4 == 0) {
      float dv = dinv[v];
      float sxv = ax + dv * x[v];
      float sdv = ad + dv;
      sx[v] = sxv; sd[v] = sdv;
      s_dv[g4] = dv;
      s_a[g4] = dv * sxv;
      s_c[g4] = dv * sdv;
      s_xr[g4] = x[root[batch[v]]];
    }
  }
  __syncthreads();

  // build z rows in bf16
  for (int idx = t; idx < 64 * ZDIM; idx += 256) {
    int r = idx / ZDIM, j = idx - r * ZDIM;
    float val;
    if (j < HID)
      val = s_a[r] * wc[j] + s_c[r] * bcv[j] + bc1[j];
    else {
      int cc = j - HID;
      val = s_xr[r] * wv[cc] + bv[cc];
    }
    zs[r][j] = (__bf16)(val > 0.f ? val : 0.f);
  }
  __syncthreads();

  int w = t >> 6, l = t & 63;
  int rb = w * 16;
  int lr = l & 15, lg = l >> 4;

  bf16x8 af[6];
#pragma unroll
  for (int kk = 0; kk < 6; ++kk)
    af[kk] = *reinterpret_cast<const bf16x8*>(&zs[rb + lr][kk * 32 + lg * 8]);

  float dvr[4];
#pragma unroll
  for (int reg = 0; reg < 4; ++reg) dvr[reg] = s_dv[rb + lg * 4 + reg];

#pragma unroll
  for (int ct = 0; ct < 8; ++ct) {
    f32x4 acc = {0.f, 0.f, 0.f, 0.f};
#pragma unroll
    for (int kk = 0; kk < 6; ++kk) {
      bf16x8 bf = *reinterpret_cast<const bf16x8*>(&wt[ct * 16 + lr][kk * 32 + lg * 8]);
      acc = __builtin_amdgcn_mfma_f32_16x16x32_bf16(af[kk], bf, acc, 0, 0, 0);
    }
#pragma unroll
    for (int reg = 0; reg < 4; ++reg) {
      int v = v0 + rb + lg * 4 + reg;
      hW2g[(size_t)v * 128 + ct * 16 + lr] = f2bf(dvr[reg] * acc[reg]);
    }
  }
}

// K9: conv2 gather (CSR, bf16 rows, 16 lanes/row, unroll-8) + relu
//     + per-graph partial-sum flush (batch is sorted)
#define GNPB 16
__global__ __launch_bounds__(256) void k_conv2(
    const int* __restrict__ off, const int* __restrict__ bsum,
    const int* __restrict__ csr,
    const uint4* __restrict__ hW2g,  // [N][16] uint4 = 128 bf16/row
    const float* __restrict__ dinv, const float* __restrict__ bc2,
    const int* __restrict__ batch, float* __restrict__ gsum) {
  __shared__ float s_out[GNPB][128];
  __shared__ int s_b[GNPB];
  int t = threadIdx.x;
  int g = t >> 4, l = t & 15;
  int v0 = blockIdx.x * GNPB;
  int v = v0 + g;
  if (t < GNPB) {
    int vv = v0 + t;
    s_b[t] = batch[vv < N_NODES ? vv : N_NODES - 1];
  }
  if (v < N_NODES) {
    const uint4* base = hW2g + l;
    float acc[8];
    {
      uint4 r = base[(size_t)v * 16];
      acc[0] = __uint_as_float(r.x << 16);
      acc[1] = __uint_as_float(r.x & 0xFFFF0000u);
      acc[2] = __uint_as_float(r.y << 16);
      acc[3] = __uint_as_float(r.y & 0xFFFF0000u);
      acc[4] = __uint_as_float(r.z << 16);
      acc[5] = __uint_as_float(r.z & 0xFFFF0000u);
      acc[6] = __uint_as_float(r.w << 16);
      acc[7] = __uint_as_float(r.w & 0xFFFF0000u);
    }
    int i = off[v] + bsum[v >> 10];
    int e = (v + 1 < N_NODES) ? off[v + 1] + bsum[(v + 1) >> 10] : off[N_NODES];
    for (; i + 8 <= e; i += 8) {
      int s0 = csr[i],     s1 = csr[i + 1], s2 = csr[i + 2], s3 = csr[i + 3];
      int s4 = csr[i + 4], s5 = csr[i + 5], s6 = csr[i + 6], s7 = csr[i + 7];
      uint4 r0 = base[(size_t)s0 * 16];
      uint4 r1 = base[(size_t)s1 * 16];
      uint4 r2 = base[(size_t)s2 * 16];
      uint4 r3 = base[(size_t)s3 * 16];
      uint4 r4 = base[(size_t)s4 * 16];
      uint4 r5 = base[(size_t)s5 * 16];
      uint4 r6 = base[(size_t)s6 * 16];
      uint4 r7 = base[(size_t)s7 * 16];
      bf8_add(acc, r0); bf8_add(acc, r1); bf8_add(acc, r2); bf8_add(acc, r3);
      bf8_add(acc, r4); bf8_add(acc, r5); bf8_add(acc, r6); bf8_add(acc, r7);
    }
    for (; i + 4 <= e; i += 4) {
      int s0 = csr[i], s1 = csr[i + 1], s2 = csr[i + 2], s3 = csr[i + 3];
      uint4 r0 = base[(size_t)s0 * 16];
      uint4 r1 = base[(size_t)s1 * 16];
      uint4 r2 = base[(size_t)s2 * 16];
      uint4 r3 = base[(size_t)s3 * 16];
      bf8_add(acc, r0); bf8_add(acc, r1); bf8_add(acc, r2); bf8_add(acc, r3);
    }
    for (; i < e; ++i) bf8_add(acc, base[(size_t)csr[i] * 16]);
    float dv = dinv[v];
#pragma unroll
    for (int j = 0; j < 8; ++j) {
      float val = dv * acc[j] + bc2[l * 8 + j];
      s_out[g][l * 8 + j] = val > 0.f ? val : 0.f;
    }
  } else {
#pragma unroll
    for (int j = 0; j < 8; ++j) s_out[g][l * 8 + j] = 0.f;
  }
  __syncthreads();
  if (t < 128) {
    int k = t;
    float local = 0.f;
    int cur = s_b[0];
    for (int m = 0; m < GNPB; ++m) {
      int b = s_b[m];
      if (b != cur) {
        atomicAdd(&gsum[cur * 128 + k], local);
        local = 0.f;
        cur = b;
      }
      local += s_out[m][k];
    }
    atomicAdd(&gsum[cur * 128 + k], local);
  }
}

// K11: finalize — mean of relu(out2) half + closed-form out1[root] half
__global__ __launch_bounds__(128) void k_final(
    const float* __restrict__ gsum, const int* __restrict__ start,
    const int* __restrict__ root, const float* __restrict__ dinv,
    const float* __restrict__ sx, const float* __restrict__ sd,
    const float* __restrict__ wc, const float* __restrict__ bcv,
    const float* __restrict__ bc1, float* __restrict__ out) {
  int b = blockIdx.x, k = threadIdx.x;
  int c = start[b + 1] - start[b];
  float cnt = (c < 1) ? 1.f : (float)c;
  out[b * 256 + k] = gsum[b * 128 + k] / cnt;
  int r = root[b];
  float dr = dinv[r];
  float a = dr * sx[r], cc = dr * sd[r];
  out[b * 256 + 128 + k] = a * wc[k] + cc * bcv[k] + bc1[k];
}

extern "C" void kernel_launch(void* const* d_in, const int* in_sizes, int n_in,
                              void* d_out, int out_size, void* d_ws, size_t ws_size,
                              hipStream_t stream) {
  const float* x   = (const float*)d_in[0];
  const int* ei    = (const int*)d_in[1];
  const int* batch = (const int*)d_in[2];
  const int* root  = (const int*)d_in[3];
  const float* W1  = (const float*)d_in[4];
  const float* b1  = (const float*)d_in[5];
  const float* W2  = (const float*)d_in[6];
  const float* b2  = (const float*)d_in[7];
  const float* W3  = (const float*)d_in[8];
  const float* b3  = (const float*)d_in[9];
  const float* Wc1 = (const float*)d_in[10];
  const float* bc1 = (const float*)d_in[11];
  const float* Wc2 = (const float*)d_in[12];
  const float* bc2 = (const float*)d_in[13];
  float* out = (float*)d_out;

  const int* src = ei;            // edge_index[0]
  const int* dst = ei + N_EDGES;  // edge_index[1]

  char* base = (char*)d_ws;
  size_t pos = 0;
  auto alloc = [&](size_t bytes) {
    size_t o = pos;
    pos = (pos + bytes + 255) & ~(size_t)255;
    return (void*)(base + o);
  };
  // NOTE: deg, cursor, gsum are allocated CONTIGUOUSLY (sizes are multiples
  // of 256) so one hipMemsetAsync zeroes all three.
  int* deg    = (int*)alloc((size_t)N_NODES * 4);          // 160000 B
  int* cursor = (int*)alloc((size_t)N_NODES * 4);          // 160000 B
  float* gsum = (float*)alloc((size_t)N_GRAPH * 128 * 4);  // 32768 B
  const size_t zero_bytes = (size_t)N_NODES * 4 * 2 + (size_t)N_GRAPH * 128 * 4;

  float* wv   = (float*)alloc(64 * 4);
  float* bv   = (float*)alloc(64 * 4);
  float* wc   = (float*)alloc(128 * 4);
  float* bcv  = (float*)alloc(128 * 4);
  float* dinv = (float*)alloc((size_t)N_NODES * 4);
  float* sx   = (float*)alloc((size_t)N_NODES * 4);
  float* sd   = (float*)alloc((size_t)N_NODES * 4);
  int* off    = (int*)alloc((size_t)(N_NODES + 1) * 4);
  int* bsum   = (int*)alloc(64 * 4);
  int* csr    = (int*)alloc((size_t)N_EDGES * 4);
  unsigned short* hW2g = (unsigned short*)alloc((size_t)N_NODES * 128 * 2);
  int* start  = (int*)alloc((size_t)(N_GRAPH + 1) * 4);
  (void)ws_size; (void)in_sizes; (void)n_in; (void)out_size;

  const int TB = 256;
  int gE = (N_EDGES + TB - 1) / TB;
  int nScanBlk = (N_NODES + 1023) / 1024;  // 40

  hipMemsetAsync(deg, 0, zero_bytes, stream);
  hipLaunchKernelGGL(k_prep, dim3(1), dim3(256), 0, stream,
                     W1, b1, W2, b2, W3, b3, Wc1, wv, bv, wc, bcv);
  hipLaunchKernelGGL(k_deg, dim3(gE), dim3(TB), 0, stream, dst, deg);
  hipLaunchKernelGGL(k_scanA, dim3(nScanBlk), dim3(256), 0, stream,
                     deg, off, bsum, dinv, batch, start);
  hipLaunchKernelGGL(k_scanB, dim3(1), dim3(64), 0, stream, bsum, off, nScanBlk);
  hipLaunchKernelGGL(k_fill, dim3(gE), dim3(TB), 0, stream,
                     src, dst, off, bsum, cursor, csr);
  hipLaunchKernelGGL(k_mlp2, dim3(N_NODES / 64), dim3(256), 0, stream,
                     x, batch, root, dinv, off, bsum, csr,
                     wc, bcv, bc1, wv, bv, Wc2, sx, sd, hW2g);
  hipLaunchKernelGGL(k_conv2, dim3(N_NODES / GNPB), dim3(256), 0, stream,
                     off, bsum, csr, (const uint4*)hW2g, dinv, bc2, batch, gsum);
  hipLaunchKernelGGL(k_final, dim3(N_GRAPH), dim3(128), 0, stream,
                     gsum, start, root, dinv, sx, sd, wc, bcv, bc1, out);
}

// Round 6
// 152.302 us; speedup vs baseline: 3.3593x; 1.0116x over previous
//
#include <hip/hip_runtime.h>
#include <hip/hip_bf16.h>

#define N_NODES 40000
#define N_EDGES 640000
#define N_GRAPH 64
#define C_IN 64
#define HID 128
#define OUT 128
#define ZDIM 192   // HID + C_IN

typedef __bf16 bf16x8 __attribute__((ext_vector_type(8)));
typedef float  f32x4  __attribute__((ext_vector_type(4)));

__device__ __forceinline__ unsigned short f2bf(float f) {
  unsigned u = __float_as_uint(f);
  unsigned r = (u + 0x7FFFu + ((u >> 16) & 1u)) >> 16;
  return (unsigned short)r;
}

__device__ __forceinline__ void bf8_add(float* acc, uint4 r) {
  acc[0] += __uint_as_float(r.x << 16);
  acc[1] += __uint_as_float(r.x & 0xFFFF0000u);
  acc[2] += __uint_as_float(r.y << 16);
  acc[3] += __uint_as_float(r.y & 0xFFFF0000u);
  acc[4] += __uint_as_float(r.z << 16);
  acc[5] += __uint_as_float(r.z & 0xFFFF0000u);
  acc[6] += __uint_as_float(r.w << 16);
  acc[7] += __uint_as_float(r.w & 0xFFFF0000u);
}

// ---------------------------------------------------------------------------
// K1: collapse the affine chains + build fragment-ordered bf16 Wc2^T.
__global__ __launch_bounds__(256) void k_prep(
    const float* __restrict__ W1, const float* __restrict__ b1,
    const float* __restrict__ W2, const float* __restrict__ b2,
    const float* __restrict__ W3, const float* __restrict__ b3,
    const float* __restrict__ Wc1, const float* __restrict__ Wc2,
    float* __restrict__ wv, float* __restrict__ bv,
    float* __restrict__ wc, float* __restrict__ bcv,
    __bf16* __restrict__ wc2t) {
  __shared__ float t1[256], u1[256], wv_s[64], bv_s[64];
  int t = threadIdx.x;
  // fragment-ordered Wc2^T: element (col,k) -> [((ct*6+kk)*64 + lg*16+lr)*8 + jj]
  for (int idx = t; idx < 128 * ZDIM; idx += 256) {
    int col = idx & 127, k = idx >> 7;       // coalesced read of Wc2[k*128+col]
    int ct = col >> 4, lr = col & 15;
    int kk = k >> 5, lg = (k >> 3) & 3, jj = k & 7;
    wc2t[((ct * 6 + kk) * 64 + lg * 16 + lr) * 8 + jj] = (__bf16)Wc2[idx];
  }
  float s1 = 0.f, s2 = 0.f;
  for (int j = 0; j < 64; ++j) {
    float w = W2[j * 256 + t];
    s1 += W1[j] * w;
    s2 += b1[j] * w;
  }
  t1[t] = s1;
  u1[t] = s2 + b2[t];
  __syncthreads();
  if (t < 64) {
    float a = 0.f, bb = 0.f;
    for (int k = 0; k < 256; ++k) {
      float w = W3[k * 64 + t];
      a += t1[k] * w;
      bb += u1[k] * w;
    }
    bb += b3[t];
    wv_s[t] = a; bv_s[t] = bb;
    wv[t] = a;  bv[t] = bb;
  }
  __syncthreads();
  if (t < 128) {
    float a = 0.f, bb = 0.f;
    for (int c = 0; c < 64; ++c) {
      float w = Wc1[c * 128 + t];
      a += wv_s[c] * w;
      bb += bv_s[c] * w;
    }
    wc[t] = a; bcv[t] = bb;
  }
}

// K3: raw in-degree (deg memset to 0; self-loop folded as deg+1 downstream)
__global__ void k_deg(const int* __restrict__ dst, int* __restrict__ deg) {
  int e = blockIdx.x * blockDim.x + threadIdx.x;
  if (e < N_EDGES) atomicAdd(&deg[dst[e]], 1);
}

// K6a: block scan of raw deg -> CSR offsets, + dinv, + per-graph segment bounds
__global__ __launch_bounds__(256) void k_scanA(const int* __restrict__ deg,
                                               int* __restrict__ off,
                                               int* __restrict__ bsum,
                                               float* __restrict__ dinv,
                                               const int* __restrict__ batch,
                                               int* __restrict__ start) {
  __shared__ int s[256];
  int t = threadIdx.x;
  int base = blockIdx.x * 1024;
  int vals[4];
  int loc = 0;
  for (int i = 0; i < 4; ++i) {
    int v = base + t * 4 + i;
    int d = 0;
    if (v < N_NODES) {
      d = deg[v];  // raw in-degree
      dinv[v] = 1.0f / sqrtf((float)(d + 1));
      int bv = batch[v];
      if (v == 0) {
        for (int b = 0; b <= bv; ++b) start[b] = 0;
      } else {
        int bp = batch[v - 1];
        for (int b = bp + 1; b <= bv; ++b) start[b] = v;
      }
      if (v == N_NODES - 1) {
        for (int b = bv + 1; b <= N_GRAPH; ++b) start[b] = N_NODES;
      }
    }
    vals[i] = loc;
    loc += d;
  }
  s[t] = loc;
  __syncthreads();
  for (int ofs = 1; ofs < 256; ofs <<= 1) {
    int a = (t >= ofs) ? s[t - ofs] : 0;
    __syncthreads();
    s[t] += a;
    __syncthreads();
  }
  int texcl = s[t] - loc;
  for (int i = 0; i < 4; ++i) {
    int v = base + t * 4 + i;
    if (v < N_NODES) off[v] = texcl + vals[i];
  }
  if (t == 255) bsum[blockIdx.x] = s[255];
}

__global__ __launch_bounds__(64) void k_scanB(int* __restrict__ bsum,
                                              int* __restrict__ off, int nb) {
  __shared__ int s[64];
  int t = threadIdx.x;
  int v = (t < nb) ? bsum[t] : 0;
  s[t] = v;
  __syncthreads();
  for (int ofs = 1; ofs < 64; ofs <<= 1) {
    int a = (t >= ofs) ? s[t - ofs] : 0;
    __syncthreads();
    s[t] += a;
    __syncthreads();
  }
  if (t < nb) bsum[t] = s[t] - v;
  if (t == 63) off[N_NODES] = s[63];
}

// K7: CSR fill (bucket by dst); final offset = off[d] + bsum[d>>10]
__global__ void k_fill(const int* __restrict__ src, const int* __restrict__ dst,
                       const int* __restrict__ off, const int* __restrict__ bsum,
                       int* __restrict__ cursor, int* __restrict__ csr_src) {
  int e = blockIdx.x * blockDim.x + threadIdx.x;
  if (e < N_EDGES) {
    int d = dst[e];
    int p = atomicAdd(&cursor[d], 1);
    csr_src[off[d] + bsum[d >> 10] + p] = src[e];
  }
}

// K8 (MFMA, no big LDS): per block = 64 nodes, 256 thr = 4 waves.
// Phase 1: fused sx/sd CSR gather (4 lanes/node) -> tiny LDS + global.
// Phase 2: A-fragments of z computed analytically IN REGISTERS;
//          B-fragments from fragment-ordered global wc2t (coalesced, L2-hot);
//          D = z @ Wc2 via mfma_f32_16x16x32_bf16; store bf16 * dinv.
__global__ __launch_bounds__(256) void k_mlp2(
    const float* __restrict__ x, const int* __restrict__ batch,
    const int* __restrict__ root, const float* __restrict__ dinv,
    const int* __restrict__ off, const int* __restrict__ bsum,
    const int* __restrict__ csr,
    const float* __restrict__ wc, const float* __restrict__ bcv,
    const float* __restrict__ bc1, const float* __restrict__ wv,
    const float* __restrict__ bv, const __bf16* __restrict__ wc2t,
    float* __restrict__ sx, float* __restrict__ sd,
    unsigned short* __restrict__ hW2g) {
  __shared__ float s_dv[64], s_a[64], s_c[64], s_xr[64];
  int t = threadIdx.x;
  int v0 = blockIdx.x * 64;

  // fused sxsd gather: 4 lanes per node (high occupancy now: no big LDS)
  {
    int g4 = t >> 2, l4 = t & 3;
    int v = v0 + g4;
    int o0 = off[v] + bsum[v >> 10];
    int o1 = (v + 1 < N_NODES) ? off[v + 1] + bsum[(v + 1) >> 10] : off[N_NODES];
    float ax = 0.f, ad = 0.f;
    for (int i = o0 + l4; i < o1; i += 4) {
      int s = csr[i];
      float ds = dinv[s];
      ax += ds * x[s];
      ad += ds;
    }
    ax += __shfl_xor(ax, 1, 4); ad += __shfl_xor(ad, 1, 4);
    ax += __shfl_xor(ax, 2, 4); ad += __shfl_xor(ad, 2, 4);
    if (l4 == 0) {
      float dv = dinv[v];
      float sxv = ax + dv * x[v];
      float sdv = ad + dv;
      sx[v] = sxv; sd[v] = sdv;
      s_dv[g4] = dv;
      s_a[g4] = dv * sxv;
      s_c[g4] = dv * sdv;
      s_xr[g4] = x[root[batch[v]]];
    }
  }
  __syncthreads();

  int w = t >> 6, l = t & 63;
  int rb = w * 16;
  int lr = l & 15, lg = l >> 4;
  int row = rb + lr;

  // A-fragments in registers: af[kk][j] = relu(z[row][kk*32+lg*8+j]) as bf16.
  // kk<4 -> conv1 half (k<128, exact since lg*8+7 <= 31+96=127); kk>=4 -> root half.
  float a = s_a[row], c = s_c[row], xr = s_xr[row];
  bf16x8 af[6];
#pragma unroll
  for (int kk = 0; kk < 4; ++kk) {
    int k0 = kk * 32 + lg * 8;
#pragma unroll
    for (int j = 0; j < 8; ++j) {
      float val = a * wc[k0 + j] + c * bcv[k0 + j] + bc1[k0 + j];
      af[kk][j] = (__bf16)(val > 0.f ? val : 0.f);
    }
  }
#pragma unroll
  for (int kk = 4; kk < 6; ++kk) {
    int k0 = (kk - 4) * 32 + lg * 8;
#pragma unroll
    for (int j = 0; j < 8; ++j) {
      float val = xr * wv[k0 + j] + bv[k0 + j];
      af[kk][j] = (__bf16)(val > 0.f ? val : 0.f);
    }
  }

  float dvr[4];
#pragma unroll
  for (int reg = 0; reg < 4; ++reg) dvr[reg] = s_dv[rb + lg * 4 + reg];

  const bf16x8* wt = (const bf16x8*)wc2t;
#pragma unroll
  for (int ct = 0; ct < 8; ++ct) {
    f32x4 acc = {0.f, 0.f, 0.f, 0.f};
#pragma unroll
    for (int kk = 0; kk < 6; ++kk) {
      bf16x8 bf = wt[(ct * 6 + kk) * 64 + l];  // coalesced 16B/lane, L2-hot
      acc = __builtin_amdgcn_mfma_f32_16x16x32_bf16(af[kk], bf, acc, 0, 0, 0);
    }
#pragma unroll
    for (int reg = 0; reg < 4; ++reg) {
      int v = v0 + rb + lg * 4 + reg;
      hW2g[(size_t)v * 128 + ct * 16 + lr] = f2bf(dvr[reg] * acc[reg]);
    }
  }
}

// K9: conv2 gather (CSR, bf16 rows, 16 lanes/row, unroll-8) + relu
//     + per-graph partial-sum flush (batch is sorted)
#define GNPB 16
__global__ __launch_bounds__(256) void k_conv2(
    const int* __restrict__ off, const int* __restrict__ bsum,
    const int* __restrict__ csr,
    const uint4* __restrict__ hW2g,  // [N][16] uint4 = 128 bf16/row
    const float* __restrict__ dinv, const float* __restrict__ bc2,
    const int* __restrict__ batch, float* __restrict__ gsum) {
  __shared__ float s_out[GNPB][128];
  __shared__ int s_b[GNPB];
  int t = threadIdx.x;
  int g = t >> 4, l = t & 15;
  int v0 = blockIdx.x * GNPB;
  int v = v0 + g;
  if (t < GNPB) {
    int vv = v0 + t;
    s_b[t] = batch[vv < N_NODES ? vv : N_NODES - 1];
  }
  if (v < N_NODES) {
    const uint4* base = hW2g + l;
    float acc[8];
    {
      uint4 r = base[(size_t)v * 16];
      acc[0] = __uint_as_float(r.x << 16);
      acc[1] = __uint_as_float(r.x & 0xFFFF0000u);
      acc[2] = __uint_as_float(r.y << 16);
      acc[3] = __uint_as_float(r.y & 0xFFFF0000u);
      acc[4] = __uint_as_float(r.z << 16);
      acc[5] = __uint_as_float(r.z & 0xFFFF0000u);
      acc[6] = __uint_as_float(r.w << 16);
      acc[7] = __uint_as_float(r.w & 0xFFFF0000u);
    }
    int i = off[v] + bsum[v >> 10];
    int e = (v + 1 < N_NODES) ? off[v + 1] + bsum[(v + 1) >> 10] : off[N_NODES];
    for (; i + 8 <= e; i += 8) {
      int s0 = csr[i],     s1 = csr[i + 1], s2 = csr[i + 2], s3 = csr[i + 3];
      int s4 = csr[i + 4], s5 = csr[i + 5], s6 = csr[i + 6], s7 = csr[i + 7];
      uint4 r0 = base[(size_t)s0 * 16];
      uint4 r1 = base[(size_t)s1 * 16];
      uint4 r2 = base[(size_t)s2 * 16];
      uint4 r3 = base[(size_t)s3 * 16];
      uint4 r4 = base[(size_t)s4 * 16];
      uint4 r5 = base[(size_t)s5 * 16];
      uint4 r6 = base[(size_t)s6 * 16];
      uint4 r7 = base[(size_t)s7 * 16];
      bf8_add(acc, r0); bf8_add(acc, r1); bf8_add(acc, r2); bf8_add(acc, r3);
      bf8_add(acc, r4); bf8_add(acc, r5); bf8_add(acc, r6); bf8_add(acc, r7);
    }
    for (; i + 4 <= e; i += 4) {
      int s0 = csr[i], s1 = csr[i + 1], s2 = csr[i + 2], s3 = csr[i + 3];
      uint4 r0 = base[(size_t)s0 * 16];
      uint4 r1 = base[(size_t)s1 * 16];
      uint4 r2 = base[(size_t)s2 * 16];
      uint4 r3 = base[(size_t)s3 * 16];
      bf8_add(acc, r0); bf8_add(acc, r1); bf8_add(acc, r2); bf8_add(acc, r3);
    }
    for (; i < e; ++i) bf8_add(acc, base[(size_t)csr[i] * 16]);
    float dv = dinv[v];
#pragma unroll
    for (int j = 0; j < 8; ++j) {
      float val = dv * acc[j] + bc2[l * 8 + j];
      s_out[g][l * 8 + j] = val > 0.f ? val : 0.f;
    }
  } else {
#pragma unroll
    for (int j = 0; j < 8; ++j) s_out[g][l * 8 + j] = 0.f;
  }
  __syncthreads();
  if (t < 128) {
    int k = t;
    float local = 0.f;
    int cur = s_b[0];
    for (int m = 0; m < GNPB; ++m) {
      int b = s_b[m];
      if (b != cur) {
        atomicAdd(&gsum[cur * 128 + k], local);
        local = 0.f;
        cur = b;
      }
      local += s_out[m][k];
    }
    atomicAdd(&gsum[cur * 128 + k], local);
  }
}

// K11: finalize — mean of relu(out2) half + closed-form out1[root] half
__global__ __launch_bounds__(128) void k_final(
    const float* __restrict__ gsum, const int* __restrict__ start,
    const int* __restrict__ root, const float* __restrict__ dinv,
    const float* __restrict__ sx, const float* __restrict__ sd,
    const float* __restrict__ wc, const float* __restrict__ bcv,
    const float* __restrict__ bc1, float* __restrict__ out) {
  int b = blockIdx.x, k = threadIdx.x;
  int c = start[b + 1] - start[b];
  float cnt = (c < 1) ? 1.f : (float)c;
  out[b * 256 + k] = gsum[b * 128 + k] / cnt;
  int r = root[b];
  float dr = dinv[r];
  float a = dr * sx[r], cc = dr * sd[r];
  out[b * 256 + 128 + k] = a * wc[k] + cc * bcv[k] + bc1[k];
}

extern "C" void kernel_launch(void* const* d_in, const int* in_sizes, int n_in,
                              void* d_out, int out_size, void* d_ws, size_t ws_size,
                              hipStream_t stream) {
  const float* x   = (const float*)d_in[0];
  const int* ei    = (const int*)d_in[1];
  const int* batch = (const int*)d_in[2];
  const int* root  = (const int*)d_in[3];
  const float* W1  = (const float*)d_in[4];
  const float* b1  = (const float*)d_in[5];
  const float* W2  = (const float*)d_in[6];
  const float* b2  = (const float*)d_in[7];
  const float* W3  = (const float*)d_in[8];
  const float* b3  = (const float*)d_in[9];
  const float* Wc1 = (const float*)d_in[10];
  const float* bc1 = (const float*)d_in[11];
  const float* Wc2 = (const float*)d_in[12];
  const float* bc2 = (const float*)d_in[13];
  float* out = (float*)d_out;

  const int* src = ei;            // edge_index[0]
  const int* dst = ei + N_EDGES;  // edge_index[1]

  char* base = (char*)d_ws;
  size_t pos = 0;
  auto alloc = [&](size_t bytes) {
    size_t o = pos;
    pos = (pos + bytes + 255) & ~(size_t)255;
    return (void*)(base + o);
  };
  // deg, cursor, gsum contiguous -> one hipMemsetAsync zeroes all three.
  int* deg    = (int*)alloc((size_t)N_NODES * 4);          // 160000 B
  int* cursor = (int*)alloc((size_t)N_NODES * 4);          // 160000 B
  float* gsum = (float*)alloc((size_t)N_GRAPH * 128 * 4);  // 32768 B
  const size_t zero_bytes = (size_t)N_NODES * 4 * 2 + (size_t)N_GRAPH * 128 * 4;

  float* wv   = (float*)alloc(64 * 4);
  float* bv   = (float*)alloc(64 * 4);
  float* wc   = (float*)alloc(128 * 4);
  float* bcv  = (float*)alloc(128 * 4);
  float* dinv = (float*)alloc((size_t)N_NODES * 4);
  float* sx   = (float*)alloc((size_t)N_NODES * 4);
  float* sd   = (float*)alloc((size_t)N_NODES * 4);
  int* off    = (int*)alloc((size_t)(N_NODES + 1) * 4);
  int* bsum   = (int*)alloc(64 * 4);
  int* csr    = (int*)alloc((size_t)N_EDGES * 4);
  unsigned short* hW2g = (unsigned short*)alloc((size_t)N_NODES * 128 * 2);
  int* start  = (int*)alloc((size_t)(N_GRAPH + 1) * 4);
  __bf16* wc2t = (__bf16*)alloc((size_t)128 * ZDIM * 2);   // fragment-ordered Wc2^T
  (void)ws_size; (void)in_sizes; (void)n_in; (void)out_size;

  const int TB = 256;
  int gE = (N_EDGES + TB - 1) / TB;
  int nScanBlk = (N_NODES + 1023) / 1024;  // 40

  hipMemsetAsync(deg, 0, zero_bytes, stream);
  hipLaunchKernelGGL(k_prep, dim3(1), dim3(256), 0, stream,
                     W1, b1, W2, b2, W3, b3, Wc1, Wc2, wv, bv, wc, bcv, wc2t);
  hipLaunchKernelGGL(k_deg, dim3(gE), dim3(TB), 0, stream, dst, deg);
  hipLaunchKernelGGL(k_scanA, dim3(nScanBlk), dim3(256), 0, stream,
                     deg, off, bsum, dinv, batch, start);
  hipLaunchKernelGGL(k_scanB, dim3(1), dim3(64), 0, stream, bsum, off, nScanBlk);
  hipLaunchKernelGGL(k_fill, dim3(gE), dim3(TB), 0, stream,
                     src, dst, off, bsum, cursor, csr);
  hipLaunchKernelGGL(k_mlp2, dim3(N_NODES / 64), dim3(256), 0, stream,
                     x, batch, root, dinv, off, bsum, csr,
                     wc, bcv, bc1, wv, bv, wc2t, sx, sd, hW2g);
  hipLaunchKernelGGL(k_conv2, dim3(N_NODES / GNPB), dim3(256), 0, stream,
                     off, bsum, csr, (const uint4*)hW2g, dinv, bc2, batch, gsum);
  hipLaunchKernelGGL(k_final, dim3(N_GRAPH), dim3(128), 0, stream,
                     gsum, start, root, dinv, sx, sd, wc, bcv, bc1, out);
}

// Round 7
// 137.462 us; speedup vs baseline: 3.7220x; 1.1080x over previous
//
#include <hip/hip_runtime.h>
#include <hip/hip_bf16.h>

#define N_NODES 40000
#define N_EDGES 640000
#define N_GRAPH 64
#define C_IN 64
#define HID 128
#define OUT 128
#define ZDIM 192   // HID + C_IN

typedef __bf16 bf16x8 __attribute__((ext_vector_type(8)));
typedef float  f32x4  __attribute__((ext_vector_type(4)));

__device__ __forceinline__ unsigned short f2bf(float f) {
  unsigned u = __float_as_uint(f);
  unsigned r = (u + 0x7FFFu + ((u >> 16) & 1u)) >> 16;
  return (unsigned short)r;
}

__device__ __forceinline__ void bf8_add(float* acc, uint4 r) {
  acc[0] += __uint_as_float(r.x << 16);
  acc[1] += __uint_as_float(r.x & 0xFFFF0000u);
  acc[2] += __uint_as_float(r.y << 16);
  acc[3] += __uint_as_float(r.y & 0xFFFF0000u);
  acc[4] += __uint_as_float(r.z << 16);
  acc[5] += __uint_as_float(r.z & 0xFFFF0000u);
  acc[6] += __uint_as_float(r.w << 16);
  acc[7] += __uint_as_float(r.w & 0xFFFF0000u);
}

// ---------------------------------------------------------------------------
// K1: collapse the affine chains. LDS-staged: each phase cooperatively
// vector-loads one weight matrix (independent dwordx4 -> one latency round),
// then computes from LDS. Avoids the serial cold-miss chains that made the
// naive version 44 us on one CU.
__global__ __launch_bounds__(256) void k_prep(
    const float* __restrict__ W1, const float* __restrict__ b1,
    const float* __restrict__ W2, const float* __restrict__ b2,
    const float* __restrict__ W3, const float* __restrict__ b3,
    const float* __restrict__ Wc1,
    float* __restrict__ wv, float* __restrict__ bv,
    float* __restrict__ wc, float* __restrict__ bcv) {
  __shared__ __align__(16) float stage[16384];   // 64 KB, reused per phase
  __shared__ float t1[256], u1[256], wv_s[64], bv_s[64], w1s[64], b1s[64];
  int t = threadIdx.x;
  float4* sv = (float4*)stage;

  // phase A: stage W2 (64x256 fp32 = 4096 float4)
  {
    const float4* W2v = (const float4*)W2;
    for (int i = t; i < 4096; i += 256) sv[i] = W2v[i];
    if (t < 64) { w1s[t] = W1[t]; b1s[t] = b1[t]; }
  }
  __syncthreads();
  {
    float s1 = 0.f, s2 = 0.f;
    for (int j = 0; j < 64; ++j) {
      float w = stage[j * 256 + t];
      s1 += w1s[j] * w;
      s2 += b1s[j] * w;
    }
    t1[t] = s1;
    u1[t] = s2 + b2[t];
  }
  __syncthreads();

  // phase B: stage W3 (256x64 fp32 = 4096 float4)
  {
    const float4* W3v = (const float4*)W3;
    for (int i = t; i < 4096; i += 256) sv[i] = W3v[i];
  }
  __syncthreads();
  if (t < 64) {
    float a = 0.f, bb = 0.f;
    for (int k = 0; k < 256; ++k) {
      float w = stage[k * 64 + t];
      a += t1[k] * w;
      bb += u1[k] * w;
    }
    bb += b3[t];
    wv_s[t] = a; bv_s[t] = bb;
    wv[t] = a;  bv[t] = bb;
  }
  __syncthreads();

  // phase C: stage Wc1 (64x128 fp32 = 2048 float4)
  {
    const float4* Wc1v = (const float4*)Wc1;
    for (int i = t; i < 2048; i += 256) sv[i] = Wc1v[i];
  }
  __syncthreads();
  if (t < 128) {
    float a = 0.f, bb = 0.f;
    for (int c = 0; c < 64; ++c) {
      float w = stage[c * 128 + t];
      a += wv_s[c] * w;
      bb += bv_s[c] * w;
    }
    wc[t] = a; bcv[t] = bb;
  }
}

// K3: raw in-degree (deg memset to 0; self-loop folded as deg+1 downstream).
// First 96 blocks also build the fragment-ordered bf16 Wc2^T (24576 elems).
__global__ void k_deg(const int* __restrict__ dst, int* __restrict__ deg,
                      const float* __restrict__ Wc2, __bf16* __restrict__ wc2t) {
  int e = blockIdx.x * blockDim.x + threadIdx.x;
  if (e < 128 * ZDIM) {
    int col = e & 127, k = e >> 7;        // coalesced read of Wc2[k*128+col]
    int ct = col >> 4, lr = col & 15;
    int kk = k >> 5, lg = (k >> 3) & 3, jj = k & 7;
    wc2t[((ct * 6 + kk) * 64 + lg * 16 + lr) * 8 + jj] = (__bf16)Wc2[e];
  }
  if (e < N_EDGES) atomicAdd(&deg[dst[e]], 1);
}

// K6a: block scan of raw deg -> CSR offsets, + dinv, + per-graph segment bounds
__global__ __launch_bounds__(256) void k_scanA(const int* __restrict__ deg,
                                               int* __restrict__ off,
                                               int* __restrict__ bsum,
                                               float* __restrict__ dinv,
                                               const int* __restrict__ batch,
                                               int* __restrict__ start) {
  __shared__ int s[256];
  int t = threadIdx.x;
  int base = blockIdx.x * 1024;
  int vals[4];
  int loc = 0;
  for (int i = 0; i < 4; ++i) {
    int v = base + t * 4 + i;
    int d = 0;
    if (v < N_NODES) {
      d = deg[v];  // raw in-degree
      dinv[v] = 1.0f / sqrtf((float)(d + 1));
      int bv = batch[v];
      if (v == 0) {
        for (int b = 0; b <= bv; ++b) start[b] = 0;
      } else {
        int bp = batch[v - 1];
        for (int b = bp + 1; b <= bv; ++b) start[b] = v;
      }
      if (v == N_NODES - 1) {
        for (int b = bv + 1; b <= N_GRAPH; ++b) start[b] = N_NODES;
      }
    }
    vals[i] = loc;
    loc += d;
  }
  s[t] = loc;
  __syncthreads();
  for (int ofs = 1; ofs < 256; ofs <<= 1) {
    int a = (t >= ofs) ? s[t - ofs] : 0;
    __syncthreads();
    s[t] += a;
    __syncthreads();
  }
  int texcl = s[t] - loc;
  for (int i = 0; i < 4; ++i) {
    int v = base + t * 4 + i;
    if (v < N_NODES) off[v] = texcl + vals[i];
  }
  if (t == 255) bsum[blockIdx.x] = s[255];
}

__global__ __launch_bounds__(64) void k_scanB(int* __restrict__ bsum,
                                              int* __restrict__ off, int nb) {
  __shared__ int s[64];
  int t = threadIdx.x;
  int v = (t < nb) ? bsum[t] : 0;
  s[t] = v;
  __syncthreads();
  for (int ofs = 1; ofs < 64; ofs <<= 1) {
    int a = (t >= ofs) ? s[t - ofs] : 0;
    __syncthreads();
    s[t] += a;
    __syncthreads();
  }
  if (t < nb) bsum[t] = s[t] - v;
  if (t == 63) off[N_NODES] = s[63];
}

// K7: CSR fill (bucket by dst); final offset = off[d] + bsum[d>>10]
__global__ void k_fill(const int* __restrict__ src, const int* __restrict__ dst,
                       const int* __restrict__ off, const int* __restrict__ bsum,
                       int* __restrict__ cursor, int* __restrict__ csr_src) {
  int e = blockIdx.x * blockDim.x + threadIdx.x;
  if (e < N_EDGES) {
    int d = dst[e];
    int p = atomicAdd(&cursor[d], 1);
    csr_src[off[d] + bsum[d >> 10] + p] = src[e];
  }
}

// K8 (MFMA, no big LDS): per block = 64 nodes, 256 thr = 4 waves.
__global__ __launch_bounds__(256) void k_mlp2(
    const float* __restrict__ x, const int* __restrict__ batch,
    const int* __restrict__ root, const float* __restrict__ dinv,
    const int* __restrict__ off, const int* __restrict__ bsum,
    const int* __restrict__ csr,
    const float* __restrict__ wc, const float* __restrict__ bcv,
    const float* __restrict__ bc1, const float* __restrict__ wv,
    const float* __restrict__ bv, const __bf16* __restrict__ wc2t,
    float* __restrict__ sx, float* __restrict__ sd,
    unsigned short* __restrict__ hW2g) {
  __shared__ float s_dv[64], s_a[64], s_c[64], s_xr[64];
  int t = threadIdx.x;
  int v0 = blockIdx.x * 64;

  // fused sxsd gather: 4 lanes per node
  {
    int g4 = t >> 2, l4 = t & 3;
    int v = v0 + g4;
    int o0 = off[v] + bsum[v >> 10];
    int o1 = (v + 1 < N_NODES) ? off[v + 1] + bsum[(v + 1) >> 10] : off[N_NODES];
    float ax = 0.f, ad = 0.f;
    for (int i = o0 + l4; i < o1; i += 4) {
      int s = csr[i];
      float ds = dinv[s];
      ax += ds * x[s];
      ad += ds;
    }
    ax += __shfl_xor(ax, 1, 4); ad += __shfl_xor(ad, 1, 4);
    ax += __shfl_xor(ax, 2, 4); ad += __shfl_xor(ad, 2, 4);
    if (l4 == 0) {
      float dv = dinv[v];
      float sxv = ax + dv * x[v];
      float sdv = ad + dv;
      sx[v] = sxv; sd[v] = sdv;
      s_dv[g4] = dv;
      s_a[g4] = dv * sxv;
      s_c[g4] = dv * sdv;
      s_xr[g4] = x[root[batch[v]]];
    }
  }
  __syncthreads();

  int w = t >> 6, l = t & 63;
  int rb = w * 16;
  int lr = l & 15, lg = l >> 4;
  int row = rb + lr;

  // A-fragments in registers: af[kk][j] = relu(z[row][kk*32+lg*8+j]) as bf16.
  float a = s_a[row], c = s_c[row], xr = s_xr[row];
  bf16x8 af[6];
#pragma unroll
  for (int kk = 0; kk < 4; ++kk) {
    int k0 = kk * 32 + lg * 8;
#pragma unroll
    for (int j = 0; j < 8; ++j) {
      float val = a * wc[k0 + j] + c * bcv[k0 + j] + bc1[k0 + j];
      af[kk][j] = (__bf16)(val > 0.f ? val : 0.f);
    }
  }
#pragma unroll
  for (int kk = 4; kk < 6; ++kk) {
    int k0 = (kk - 4) * 32 + lg * 8;
#pragma unroll
    for (int j = 0; j < 8; ++j) {
      float val = xr * wv[k0 + j] + bv[k0 + j];
      af[kk][j] = (__bf16)(val > 0.f ? val : 0.f);
    }
  }

  float dvr[4];
#pragma unroll
  for (int reg = 0; reg < 4; ++reg) dvr[reg] = s_dv[rb + lg * 4 + reg];

  const bf16x8* wt = (const bf16x8*)wc2t;
#pragma unroll
  for (int ct = 0; ct < 8; ++ct) {
    f32x4 acc = {0.f, 0.f, 0.f, 0.f};
#pragma unroll
    for (int kk = 0; kk < 6; ++kk) {
      bf16x8 bf = wt[(ct * 6 + kk) * 64 + l];  // coalesced 16B/lane, L2-hot
      acc = __builtin_amdgcn_mfma_f32_16x16x32_bf16(af[kk], bf, acc, 0, 0, 0);
    }
#pragma unroll
    for (int reg = 0; reg < 4; ++reg) {
      int v = v0 + rb + lg * 4 + reg;
      hW2g[(size_t)v * 128 + ct * 16 + lr] = f2bf(dvr[reg] * acc[reg]);
    }
  }
}

// K9: conv2 gather (CSR, bf16 rows, 16 lanes/row, unroll-8) + relu
//     + per-graph partial-sum flush (batch is sorted)
#define GNPB 16
__global__ __launch_bounds__(256) void k_conv2(
    const int* __restrict__ off, const int* __restrict__ bsum,
    const int* __restrict__ csr,
    const uint4* __restrict__ hW2g,  // [N][16] uint4 = 128 bf16/row
    const float* __restrict__ dinv, const float* __restrict__ bc2,
    const int* __restrict__ batch, float* __restrict__ gsum) {
  __shared__ float s_out[GNPB][128];
  __shared__ int s_b[GNPB];
  int t = threadIdx.x;
  int g = t >> 4, l = t & 15;
  int v0 = blockIdx.x * GNPB;
  int v = v0 + g;
  if (t < GNPB) {
    int vv = v0 + t;
    s_b[t] = batch[vv < N_NODES ? vv : N_NODES - 1];
  }
  if (v < N_NODES) {
    const uint4* base = hW2g + l;
    float acc[8];
    {
      uint4 r = base[(size_t)v * 16];
      acc[0] = __uint_as_float(r.x << 16);
      acc[1] = __uint_as_float(r.x & 0xFFFF0000u);
      acc[2] = __uint_as_float(r.y << 16);
      acc[3] = __uint_as_float(r.y & 0xFFFF0000u);
      acc[4] = __uint_as_float(r.z << 16);
      acc[5] = __uint_as_float(r.z & 0xFFFF0000u);
      acc[6] = __uint_as_float(r.w << 16);
      acc[7] = __uint_as_float(r.w & 0xFFFF0000u);
    }
    int i = off[v] + bsum[v >> 10];
    int e = (v + 1 < N_NODES) ? off[v + 1] + bsum[(v + 1) >> 10] : off[N_NODES];
    for (; i + 8 <= e; i += 8) {
      int s0 = csr[i],     s1 = csr[i + 1], s2 = csr[i + 2], s3 = csr[i + 3];
      int s4 = csr[i + 4], s5 = csr[i + 5], s6 = csr[i + 6], s7 = csr[i + 7];
      uint4 r0 = base[(size_t)s0 * 16];
      uint4 r1 = base[(size_t)s1 * 16];
      uint4 r2 = base[(size_t)s2 * 16];
      uint4 r3 = base[(size_t)s3 * 16];
      uint4 r4 = base[(size_t)s4 * 16];
      uint4 r5 = base[(size_t)s5 * 16];
      uint4 r6 = base[(size_t)s6 * 16];
      uint4 r7 = base[(size_t)s7 * 16];
      bf8_add(acc, r0); bf8_add(acc, r1); bf8_add(acc, r2); bf8_add(acc, r3);
      bf8_add(acc, r4); bf8_add(acc, r5); bf8_add(acc, r6); bf8_add(acc, r7);
    }
    for (; i + 4 <= e; i += 4) {
      int s0 = csr[i], s1 = csr[i + 1], s2 = csr[i + 2], s3 = csr[i + 3];
      uint4 r0 = base[(size_t)s0 * 16];
      uint4 r1 = base[(size_t)s1 * 16];
      uint4 r2 = base[(size_t)s2 * 16];
      uint4 r3 = base[(size_t)s3 * 16];
      bf8_add(acc, r0); bf8_add(acc, r1); bf8_add(acc, r2); bf8_add(acc, r3);
    }
    for (; i < e; ++i) bf8_add(acc, base[(size_t)csr[i] * 16]);
    float dv = dinv[v];
#pragma unroll
    for (int j = 0; j < 8; ++j) {
      float val = dv * acc[j] + bc2[l * 8 + j];
      s_out[g][l * 8 + j] = val > 0.f ? val : 0.f;
    }
  } else {
#pragma unroll
    for (int j = 0; j < 8; ++j) s_out[g][l * 8 + j] = 0.f;
  }
  __syncthreads();
  if (t < 128) {
    int k = t;
    float local = 0.f;
    int cur = s_b[0];
    for (int m = 0; m < GNPB; ++m) {
      int b = s_b[m];
      if (b != cur) {
        atomicAdd(&gsum[cur * 128 + k], local);
        local = 0.f;
        cur = b;
      }
      local += s_out[m][k];
    }
    atomicAdd(&gsum[cur * 128 + k], local);
  }
}

// K11: finalize — mean of relu(out2) half + closed-form out1[root] half
__global__ __launch_bounds__(128) void k_final(
    const float* __restrict__ gsum, const int* __restrict__ start,
    const int* __restrict__ root, const float* __restrict__ dinv,
    const float* __restrict__ sx, const float* __restrict__ sd,
    const float* __restrict__ wc, const float* __restrict__ bcv,
    const float* __restrict__ bc1, float* __restrict__ out) {
  int b = blockIdx.x, k = threadIdx.x;
  int c = start[b + 1] - start[b];
  float cnt = (c < 1) ? 1.f : (float)c;
  out[b * 256 + k] = gsum[b * 128 + k] / cnt;
  int r = root[b];
  float dr = dinv[r];
  float a = dr * sx[r], cc = dr * sd[r];
  out[b * 256 + 128 + k] = a * wc[k] + cc * bcv[k] + bc1[k];
}

extern "C" void kernel_launch(void* const* d_in, const int* in_sizes, int n_in,
                              void* d_out, int out_size, void* d_ws, size_t ws_size,
                              hipStream_t stream) {
  const float* x   = (const float*)d_in[0];
  const int* ei    = (const int*)d_in[1];
  const int* batch = (const int*)d_in[2];
  const int* root  = (const int*)d_in[3];
  const float* W1  = (const float*)d_in[4];
  const float* b1  = (const float*)d_in[5];
  const float* W2  = (const float*)d_in[6];
  const float* b2  = (const float*)d_in[7];
  const float* W3  = (const float*)d_in[8];
  const float* b3  = (const float*)d_in[9];
  const float* Wc1 = (const float*)d_in[10];
  const float* bc1 = (const float*)d_in[11];
  const float* Wc2 = (const float*)d_in[12];
  const float* bc2 = (const float*)d_in[13];
  float* out = (float*)d_out;

  const int* src = ei;            // edge_index[0]
  const int* dst = ei + N_EDGES;  // edge_index[1]

  char* base = (char*)d_ws;
  size_t pos = 0;
  auto alloc = [&](size_t bytes) {
    size_t o = pos;
    pos = (pos + bytes + 255) & ~(size_t)255;
    return (void*)(base + o);
  };
  // deg, cursor, gsum contiguous -> one hipMemsetAsync zeroes all three.
  int* deg    = (int*)alloc((size_t)N_NODES * 4);          // 160000 B
  int* cursor = (int*)alloc((size_t)N_NODES * 4);          // 160000 B
  float* gsum = (float*)alloc((size_t)N_GRAPH * 128 * 4);  // 32768 B
  const size_t zero_bytes = (size_t)N_NODES * 4 * 2 + (size_t)N_GRAPH * 128 * 4;

  float* wv   = (float*)alloc(64 * 4);
  float* bv   = (float*)alloc(64 * 4);
  float* wc   = (float*)alloc(128 * 4);
  float* bcv  = (float*)alloc(128 * 4);
  float* dinv = (float*)alloc((size_t)N_NODES * 4);
  float* sx   = (float*)alloc((size_t)N_NODES * 4);
  float* sd   = (float*)alloc((size_t)N_NODES * 4);
  int* off    = (int*)alloc((size_t)(N_NODES + 1) * 4);
  int* bsum   = (int*)alloc(64 * 4);
  int* csr    = (int*)alloc((size_t)N_EDGES * 4);
  unsigned short* hW2g = (unsigned short*)alloc((size_t)N_NODES * 128 * 2);
  int* start  = (int*)alloc((size_t)(N_GRAPH + 1) * 4);
  __bf16* wc2t = (__bf16*)alloc((size_t)128 * ZDIM * 2);   // fragment-ordered Wc2^T
  (void)ws_size; (void)in_sizes; (void)n_in; (void)out_size;

  const int TB = 256;
  int gE = (N_EDGES + TB - 1) / TB;
  int nScanBlk = (N_NODES + 1023) / 1024;  // 40

  hipMemsetAsync(deg, 0, zero_bytes, stream);
  hipLaunchKernelGGL(k_prep, dim3(1), dim3(256), 0, stream,
                     W1, b1, W2, b2, W3, b3, Wc1, wv, bv, wc, bcv);
  hipLaunchKernelGGL(k_deg, dim3(gE), dim3(TB), 0, stream, dst, deg, Wc2, wc2t);
  hipLaunchKernelGGL(k_scanA, dim3(nScanBlk), dim3(256), 0, stream,
                     deg, off, bsum, dinv, batch, start);
  hipLaunchKernelGGL(k_scanB, dim3(1), dim3(64), 0, stream, bsum, off, nScanBlk);
  hipLaunchKernelGGL(k_fill, dim3(gE), dim3(TB), 0, stream,
                     src, dst, off, bsum, cursor, csr);
  hipLaunchKernelGGL(k_mlp2, dim3(N_NODES / 64), dim3(256), 0, stream,
                     x, batch, root, dinv, off, bsum, csr,
                     wc, bcv, bc1, wv, bv, wc2t, sx, sd, hW2g);
  hipLaunchKernelGGL(k_conv2, dim3(N_NODES / GNPB), dim3(256), 0, stream,
                     off, bsum, csr, (const uint4*)hW2g, dinv, bc2, batch, gsum);
  hipLaunchKernelGGL(k_final, dim3(N_GRAPH), dim3(128), 0, stream,
                     gsum, start, root, dinv, sx, sd, wc, bcv, bc1, out);
}